// Round 1
// baseline (1856.202 us; speedup 1.0000x reference)
//
#include <hip/hip_runtime.h>
#include <math.h>

#define NMOL 256
#define NATOM 384
#define NN (NMOL*NATOM)          // 98304
#define AEV 384
#define D1 160
#define D2 128
#define D3 96
#define A0_INV (1.0f/0.529177249f)

__constant__ float c_sigma[8] = {0.5515909f, 1.8886297f, 1.3225029f, 1.2316629f,
                                 2.1884933f, 1.7750372f, 1.3677907f, 1.3820058f};

__device__ __forceinline__ float celu01(float v) {
    return v > 0.f ? v : 0.1f * expm1f(10.f * v);
}

// ---------------- GEMM: C = celu(A @ W^T + b) ----------------
// A: M x LDA_K row-major (k-loop over KLOOP cols)
// W: N x LDW row-major
// LAYER1: adds q[row]*W[col][384] + esp[row]*W[col][385] before bias/celu
#define BM 128
#define BN 32
#define BK 16

template<int LDA_K, int KLOOP, int LDW, bool LAYER1>
__global__ __launch_bounds__(256)
void gemm_celu(const float* __restrict__ A, const float* __restrict__ W,
               const float* __restrict__ bias,
               const float* __restrict__ qv, const float* __restrict__ espv,
               float* __restrict__ C, int Ntot)
{
    __shared__ float As[BK][BM];
    __shared__ float Bs[BK][BN];
    const int t  = threadIdx.x;
    const int n0 = blockIdx.x * BN;
    const int m0 = blockIdx.y * BM;
    const int tx = t & 7;    // 8 groups of 4 cols
    const int ty = t >> 3;   // 32 groups of 4 rows

    float acc[4][4] = {};

    for (int k0 = 0; k0 < KLOOP; k0 += BK) {
        // A tile: 128 rows x 16 cols = 512 float4, 2 per thread
        #pragma unroll
        for (int i = 0; i < 2; ++i) {
            int v = t + i * 256;
            int row = v >> 2;
            int c = (v & 3) * 4;
            const float4 f = *reinterpret_cast<const float4*>(
                A + (size_t)(m0 + row) * LDA_K + k0 + c);
            As[c+0][row] = f.x; As[c+1][row] = f.y;
            As[c+2][row] = f.z; As[c+3][row] = f.w;
        }
        // B tile: 32 rows x 16 cols = 512 floats, 2 per thread (scalar: LDW may be odd)
        #pragma unroll
        for (int i = 0; i < 2; ++i) {
            int v = t + i * 256;
            int row = v >> 4;
            int c = v & 15;
            Bs[c][row] = W[(size_t)(n0 + row) * LDW + k0 + c];
        }
        __syncthreads();
        #pragma unroll
        for (int k = 0; k < BK; ++k) {
            float4 a = *reinterpret_cast<const float4*>(&As[k][ty * 4]);
            float4 b = *reinterpret_cast<const float4*>(&Bs[k][tx * 4]);
            float av[4] = {a.x, a.y, a.z, a.w};
            float bv[4] = {b.x, b.y, b.z, b.w};
            #pragma unroll
            for (int i = 0; i < 4; ++i)
                #pragma unroll
                for (int j = 0; j < 4; ++j)
                    acc[i][j] = fmaf(av[i], bv[j], acc[i][j]);
        }
        __syncthreads();
    }

    #pragma unroll
    for (int i = 0; i < 4; ++i) {
        int row = m0 + ty * 4 + i;
        float qr = 0.f, er = 0.f;
        if (LAYER1) { qr = qv[row]; er = espv[row]; }
        #pragma unroll
        for (int j = 0; j < 4; ++j) {
            int col = n0 + tx * 4 + j;
            float v = acc[i][j];
            if (LAYER1)
                v += qr * W[(size_t)col * LDW + 384] + er * W[(size_t)col * LDW + 385];
            v += bias[col];
            C[(size_t)row * Ntot + col] = celu01(v);
        }
    }
}

// ---------------- layer 4: chi = mask * softplus(h3 @ W4^T + b4) ----------------
__global__ __launch_bounds__(256)
void chi_kernel(const float* __restrict__ h3, const float* __restrict__ W4,
                const float* __restrict__ b4, const int* __restrict__ species,
                float* __restrict__ chi)
{
    __shared__ float w[D3];
    int t = threadIdx.x;
    if (t < D3) w[t] = W4[t];
    __syncthreads();
    int atom = blockIdx.x * 256 + t;
    const float* row = h3 + (size_t)atom * D3;
    float s = 0.f;
    #pragma unroll
    for (int c = 0; c < D3; c += 4) {
        float4 f = *reinterpret_cast<const float4*>(row + c);
        s = fmaf(f.x, w[c+0], s); s = fmaf(f.y, w[c+1], s);
        s = fmaf(f.z, w[c+2], s); s = fmaf(f.w, w[c+3], s);
    }
    s += b4[0];
    s = fmaxf(s, 0.f) + log1pf(expf(-fabsf(s)));   // softplus
    chi[atom] = (species[atom] != -1) ? s : 0.f;
}

// ---------------- per-molecule charge normalization ----------------
__global__ __launch_bounds__(384)
void charge_kernel(const float* __restrict__ chi, const int* __restrict__ species,
                   const float* __restrict__ netq, float* __restrict__ q)
{
    __shared__ float red[512];
    __shared__ float redc[512];
    int m = blockIdx.x, j = threadIdx.x;
    int idx = m * NATOM + j;
    float c = chi[idx];
    float mask = (species[idx] != -1) ? 1.f : 0.f;
    red[j] = c; redc[j] = mask;
    if (j < 128) { red[NATOM + j] = 0.f; redc[NATOM + j] = 0.f; }
    __syncthreads();
    for (int s = 256; s > 0; s >>= 1) {
        if (j < s) { red[j] += red[j + s]; redc[j] += redc[j + s]; }
        __syncthreads();
    }
    float chi_sum = red[0];
    float na = redc[0];
    float Q = netq[m];
    float k_net = 1.f + fabsf(Q) / chi_sum;
    float chi_mean = chi_sum / na;
    float k_p = (Q > 0.f) ? k_net : 1.f;
    float k_n = (Q < 0.f) ? k_net : 1.f;
    q[idx] = (-k_n * c + k_p * chi_mean) * mask;
}

// ---------------- ESP: esp_j = mask_j * sum_{i != j} q_i * erf(d/sqrt(2(s_i^2+s_j^2)))/d ----------------
__global__ __launch_bounds__(384)
void esp_kernel(const float* __restrict__ coords, const int* __restrict__ species,
                const float* __restrict__ q, float* __restrict__ esp)
{
    __shared__ float cx[NATOM], cy[NATOM], cz[NATOM], s2[NATOM], qs[NATOM];
    int m = blockIdx.x, j = threadIdx.x;
    int idx = m * NATOM + j;
    float3 r;
    r.x = coords[(size_t)idx * 3 + 0];
    r.y = coords[(size_t)idx * 3 + 1];
    r.z = coords[(size_t)idx * 3 + 2];
    cx[j] = r.x; cy[j] = r.y; cz[j] = r.z;
    int sp = species[idx];
    float sig = c_sigma[sp < 0 ? 7 : sp];
    s2[j] = sig * sig;
    qs[j] = q[idx];
    bool maskj = (sp != -1);
    __syncthreads();
    float s2j = s2[j];
    float acc = 0.f;
    for (int i = 0; i < NATOM; ++i) {
        float dx = cx[i] - r.x, dy = cy[i] - r.y, dz = cz[i] - r.z;
        float d2 = fmaf(dx, dx, fmaf(dy, dy, dz * dz)) + 1e-16f;
        float d = sqrtf(d2) * A0_INV;
        float ss = fmaxf(s2[i] + s2j, 1e-8f);
        float val = erff(d * rsqrtf(2.f * ss)) / d;
        acc += (i == j) ? 0.f : qs[i] * val;
    }
    esp[idx] = maskj ? acc : 0.f;
}

// ---------------- output: [species as float | charges] ----------------
__global__ __launch_bounds__(256)
void out_kernel(const int* __restrict__ species, const float* __restrict__ q,
                float* __restrict__ out)
{
    int i = blockIdx.x * 256 + threadIdx.x;
    out[i] = (float)species[i];
    out[NN + i] = q[i];
}

extern "C" void kernel_launch(void* const* d_in, const int* in_sizes, int n_in,
                              void* d_out, int out_size, void* d_ws, size_t ws_size,
                              hipStream_t stream)
{
    const int*   species = (const int*)  d_in[0];
    const float* coords  = (const float*)d_in[1];
    const float* netq    = (const float*)d_in[2];
    const float* aev     = (const float*)d_in[3];
    const float* W1 = (const float*)d_in[4];
    const float* b1 = (const float*)d_in[5];
    const float* W2 = (const float*)d_in[6];
    const float* b2 = (const float*)d_in[7];
    const float* W3 = (const float*)d_in[8];
    const float* b3 = (const float*)d_in[9];
    const float* W4 = (const float*)d_in[10];
    const float* b4 = (const float*)d_in[11];

    float* ws  = (float*)d_ws;
    float* q   = ws;                       // NN
    float* esp = ws + NN;                  // NN
    float* chi = ws + 2 * (size_t)NN;      // NN
    float* h1  = ws + 3 * (size_t)NN;      // NN * 160  (also reused for h3)
    float* h2  = h1 + (size_t)NN * D1;     // NN * 128
    float* h3  = h1;                       // h1 dead once h2 is built

    // q = esp = 0 for iteration 0
    hipMemsetAsync(ws, 0, 2 * (size_t)NN * sizeof(float), stream);

    for (int it = 0; it < 4; ++it) {
        gemm_celu<AEV, AEV, 386, true>
            <<<dim3(D1 / BN, NN / BM), 256, 0, stream>>>(aev, W1, b1, q, esp, h1, D1);
        gemm_celu<D1, D1, D1, false>
            <<<dim3(D2 / BN, NN / BM), 256, 0, stream>>>(h1, W2, b2, nullptr, nullptr, h2, D2);
        gemm_celu<D2, D2, D2, false>
            <<<dim3(D3 / BN, NN / BM), 256, 0, stream>>>(h2, W3, b3, nullptr, nullptr, h3, D3);
        chi_kernel<<<NN / 256, 256, 0, stream>>>(h3, W4, b4, species, chi);
        charge_kernel<<<NMOL, NATOM, 0, stream>>>(chi, species, netq, q);
        esp_kernel<<<NMOL, NATOM, 0, stream>>>(coords, species, q, esp);
    }

    out_kernel<<<NN / 256, 256, 0, stream>>>(species, q, (float*)d_out);
}

// Round 2
// 950.945 us; speedup vs baseline: 1.9520x; 1.9520x over previous
//
#include <hip/hip_runtime.h>
#include <math.h>

#define NMOL 256
#define NATOM 384
#define NN (NMOL*NATOM)          // 98304
#define A0_INV (1.0f/0.529177249f)

typedef short bf16x8 __attribute__((ext_vector_type(8)));
typedef float f32x4  __attribute__((ext_vector_type(4)));
typedef float f32x4u __attribute__((ext_vector_type(4), aligned(4)));

__constant__ float c_sigma[8] = {0.5515909f, 1.8886297f, 1.3225029f, 1.2316629f,
                                 2.1884933f, 1.7750372f, 1.3677907f, 1.3820058f};

__device__ __forceinline__ short f2b(float f) {           // f32 -> bf16 RNE
    unsigned u = __float_as_uint(f);
    u = (u + 0x7fffu + ((u >> 16) & 1u)) >> 16;
    return (short)u;
}
__device__ __forceinline__ float b2f(short s) {
    return __uint_as_float(((unsigned)(unsigned short)s) << 16);
}
__device__ __forceinline__ float celu01(float v) {
    return v > 0.f ? v : 0.1f * expm1f(10.f * v);
}
__device__ __forceinline__ bf16x8 cvt8(f32x4u a, f32x4u b) {
    bf16x8 r;
    r[0] = f2b(a.x); r[1] = f2b(a.y); r[2] = f2b(a.z); r[3] = f2b(a.w);
    r[4] = f2b(b.x); r[5] = f2b(b.y); r[6] = f2b(b.z); r[7] = f2b(b.w);
    return r;
}

// ============ MFMA GEMM: C(bf16) = celu(A @ W^T + b [+ q*wq + esp*we]) ============
// A: [M][K] (fp32 if AF32 else bf16), W: [N][LDW] fp32, C: [M][N] bf16
// block = 256 thr = 4 waves (2x2), BM=128, full N per block, BK=32
template<int N, int K, int LDW, bool AF32, bool L1F>
__global__ __launch_bounds__(256, 3)
void mlp_gemm(const void* __restrict__ Aptr, const float* __restrict__ W,
              const float* __restrict__ bias, const float* __restrict__ qv,
              const float* __restrict__ espv, short* __restrict__ Cout)
{
    constexpr int N2 = N / 2;       // cols per wave
    constexpr int NF = N / 32;      // 16-col frags per wave
    constexpr int PAD = 40;         // shorts per LDS row (32 data + 8 pad -> bank-uniform)
    __shared__ short As[128 * PAD];
    __shared__ short Bs[N * PAD];

    const int t    = threadIdx.x;
    const int lane = t & 63;
    const int wave = t >> 6;
    const int wm   = wave >> 1;     // row half (64 rows)
    const int wn   = wave & 1;      // col half (N/2)
    const int l15  = lane & 15;
    const int l4   = lane >> 4;
    const int m0   = blockIdx.x * 128;
    const int srow  = t >> 1;       // staging: A row
    const int shalf = t & 1;        // staging: 16-elem half

    f32x4 acc[4][NF] = {};

    for (int k0 = 0; k0 < K; k0 += 32) {
        // ---- stage A tile (128 x 32) ----
        if (AF32) {
            const float* A = (const float*)Aptr;
            const float* s = A + (size_t)(m0 + srow) * K + k0 + shalf * 16;
            f32x4u f0 = *(const f32x4u*)(s + 0);
            f32x4u f1 = *(const f32x4u*)(s + 4);
            f32x4u f2 = *(const f32x4u*)(s + 8);
            f32x4u f3 = *(const f32x4u*)(s + 12);
            *(bf16x8*)&As[srow * PAD + shalf * 16 + 0] = cvt8(f0, f1);
            *(bf16x8*)&As[srow * PAD + shalf * 16 + 8] = cvt8(f2, f3);
        } else {
            const short* A = (const short*)Aptr;
            const short* s = A + (size_t)(m0 + srow) * K + k0 + shalf * 16;
            *(bf16x8*)&As[srow * PAD + shalf * 16 + 0] = *(const bf16x8*)(s + 0);
            *(bf16x8*)&As[srow * PAD + shalf * 16 + 8] = *(const bf16x8*)(s + 8);
        }
        // ---- stage B tile (N x 32) from fp32 W ----
        #pragma unroll
        for (int id0 = 0; id0 < N * 2; id0 += 256) {
            int id = id0 + t;
            if (id < N * 2) {
                int row = id >> 1, half = id & 1;
                const float* s = W + (size_t)row * LDW + k0 + half * 16;
                f32x4u f0 = *(const f32x4u*)(s + 0);
                f32x4u f1 = *(const f32x4u*)(s + 4);
                f32x4u f2 = *(const f32x4u*)(s + 8);
                f32x4u f3 = *(const f32x4u*)(s + 12);
                *(bf16x8*)&Bs[row * PAD + half * 16 + 0] = cvt8(f0, f1);
                *(bf16x8*)&Bs[row * PAD + half * 16 + 8] = cvt8(f2, f3);
            }
        }
        __syncthreads();
        // ---- frags + MFMA ----
        bf16x8 a[4];
        #pragma unroll
        for (int mf = 0; mf < 4; ++mf)
            a[mf] = *(const bf16x8*)&As[(wm * 64 + mf * 16 + l15) * PAD + l4 * 8];
        #pragma unroll
        for (int nf = 0; nf < NF; ++nf) {
            bf16x8 b = *(const bf16x8*)&Bs[(wn * N2 + nf * 16 + l15) * PAD + l4 * 8];
            #pragma unroll
            for (int mf = 0; mf < 4; ++mf)
                acc[mf][nf] = __builtin_amdgcn_mfma_f32_16x16x32_bf16(a[mf], b, acc[mf][nf], 0, 0, 0);
        }
        __syncthreads();
    }

    // ---- epilogue: bias [+ q/esp features] + celu, store bf16 ----
    float qr[4][4], er[4][4];
    if (L1F) {
        #pragma unroll
        for (int mf = 0; mf < 4; ++mf)
            #pragma unroll
            for (int r = 0; r < 4; ++r) {
                int row = m0 + wm * 64 + mf * 16 + l4 * 4 + r;
                qr[mf][r] = qv[row];
                er[mf][r] = espv[row];
            }
    }
    #pragma unroll
    for (int nf = 0; nf < NF; ++nf) {
        int col = wn * N2 + nf * 16 + l15;
        float bc = bias[col];
        float wq = 0.f, we = 0.f;
        if (L1F) {
            wq = W[(size_t)col * LDW + K];
            we = W[(size_t)col * LDW + K + 1];
        }
        #pragma unroll
        for (int mf = 0; mf < 4; ++mf)
            #pragma unroll
            for (int r = 0; r < 4; ++r) {
                float v = acc[mf][nf][r] + bc;
                if (L1F) v += qr[mf][r] * wq + er[mf][r] * we;
                v = celu01(v);
                int row = m0 + wm * 64 + mf * 16 + l4 * 4 + r;
                Cout[(size_t)row * N + col] = f2b(v);
            }
    }
}

// ---------------- layer 4: chi = mask * softplus(h3 @ W4^T + b4) ----------------
__global__ __launch_bounds__(256)
void chi_kernel(const short* __restrict__ h3, const float* __restrict__ W4,
                const float* __restrict__ b4, const int* __restrict__ species,
                float* __restrict__ chi)
{
    __shared__ float w[96];
    int t = threadIdx.x;
    if (t < 96) w[t] = W4[t];
    __syncthreads();
    int atom = blockIdx.x * 256 + t;
    const short* row = h3 + (size_t)atom * 96;
    float s = 0.f;
    #pragma unroll
    for (int c = 0; c < 96; c += 8) {
        bf16x8 v = *(const bf16x8*)(row + c);
        #pragma unroll
        for (int j = 0; j < 8; ++j) s = fmaf(b2f(v[j]), w[c + j], s);
    }
    s += b4[0];
    s = fmaxf(s, 0.f) + log1pf(expf(-fabsf(s)));   // softplus
    chi[atom] = (species[atom] != -1) ? s : 0.f;
}

// ---------------- per-molecule charge normalization ----------------
__global__ __launch_bounds__(384)
void charge_kernel(const float* __restrict__ chi, const int* __restrict__ species,
                   const float* __restrict__ netq, float* __restrict__ q)
{
    __shared__ float red[512];
    __shared__ float redc[512];
    int m = blockIdx.x, j = threadIdx.x;
    int idx = m * NATOM + j;
    float c = chi[idx];
    float mask = (species[idx] != -1) ? 1.f : 0.f;
    red[j] = c; redc[j] = mask;
    if (j < 128) { red[NATOM + j] = 0.f; redc[NATOM + j] = 0.f; }
    __syncthreads();
    for (int s = 256; s > 0; s >>= 1) {
        if (j < s) { red[j] += red[j + s]; redc[j] += redc[j + s]; }
        __syncthreads();
    }
    float chi_sum = red[0];
    float na = redc[0];
    float Q = netq[m];
    float k_net = 1.f + fabsf(Q) / chi_sum;
    float chi_mean = chi_sum / na;
    float k_p = (Q > 0.f) ? k_net : 1.f;
    float k_n = (Q < 0.f) ? k_net : 1.f;
    q[idx] = (-k_n * c + k_p * chi_mean) * mask;
}

// ---------------- ESP: esp_j = mask_j * sum_{i != j} q_i * erf(d/sqrt(2(si^2+sj^2)))/d ----------------
__global__ __launch_bounds__(384)
void esp_kernel(const float* __restrict__ coords, const int* __restrict__ species,
                const float* __restrict__ q, float* __restrict__ esp)
{
    __shared__ float cx[NATOM], cy[NATOM], cz[NATOM], s2[NATOM], qs[NATOM];
    int m = blockIdx.x, j = threadIdx.x;
    int idx = m * NATOM + j;
    float3 r;
    r.x = coords[(size_t)idx * 3 + 0];
    r.y = coords[(size_t)idx * 3 + 1];
    r.z = coords[(size_t)idx * 3 + 2];
    cx[j] = r.x; cy[j] = r.y; cz[j] = r.z;
    int sp = species[idx];
    float sig = c_sigma[sp < 0 ? 7 : sp];
    s2[j] = sig * sig;
    qs[j] = q[idx];
    bool maskj = (sp != -1);
    __syncthreads();
    float s2j = s2[j];
    float acc = 0.f;
    for (int i = 0; i < NATOM; ++i) {
        float dx = cx[i] - r.x, dy = cy[i] - r.y, dz = cz[i] - r.z;
        float d2 = fmaf(dx, dx, fmaf(dy, dy, dz * dz)) + 1e-16f;
        float d = sqrtf(d2) * A0_INV;
        float ss = fmaxf(s2[i] + s2j, 1e-8f);
        float val = erff(d * rsqrtf(2.f * ss)) / d;
        acc += (i == j) ? 0.f : qs[i] * val;
    }
    esp[idx] = maskj ? acc : 0.f;
}

// ---------------- output: [species as float | charges] ----------------
__global__ __launch_bounds__(256)
void out_kernel(const int* __restrict__ species, const float* __restrict__ q,
                float* __restrict__ out)
{
    int i = blockIdx.x * 256 + threadIdx.x;
    out[i] = (float)species[i];
    out[NN + i] = q[i];
}

extern "C" void kernel_launch(void* const* d_in, const int* in_sizes, int n_in,
                              void* d_out, int out_size, void* d_ws, size_t ws_size,
                              hipStream_t stream)
{
    const int*   species = (const int*)  d_in[0];
    const float* coords  = (const float*)d_in[1];
    const float* netq    = (const float*)d_in[2];
    const float* aev     = (const float*)d_in[3];
    const float* W1 = (const float*)d_in[4];
    const float* b1 = (const float*)d_in[5];
    const float* W2 = (const float*)d_in[6];
    const float* b2 = (const float*)d_in[7];
    const float* W3 = (const float*)d_in[8];
    const float* b3 = (const float*)d_in[9];
    const float* W4 = (const float*)d_in[10];
    const float* b4 = (const float*)d_in[11];

    float* ws  = (float*)d_ws;
    float* q   = ws;                        // NN f32
    float* esp = ws + NN;                   // NN f32
    float* chi = ws + 2 * (size_t)NN;       // NN f32
    short* h1  = (short*)(ws + 3 * (size_t)NN);   // NN x 160 bf16
    short* h2  = h1 + (size_t)NN * 160;           // NN x 128 bf16
    short* h3  = h1;                              // reuse (h1 dead after L2)

    hipMemsetAsync(ws, 0, 2 * (size_t)NN * sizeof(float), stream);  // q = esp = 0

    for (int it = 0; it < 4; ++it) {
        mlp_gemm<160, 384, 386, true,  true >
            <<<NN / 128, 256, 0, stream>>>(aev, W1, b1, q, esp, h1);
        mlp_gemm<128, 160, 160, false, false>
            <<<NN / 128, 256, 0, stream>>>(h1, W2, b2, nullptr, nullptr, h2);
        mlp_gemm< 96, 128, 128, false, false>
            <<<NN / 128, 256, 0, stream>>>(h2, W3, b3, nullptr, nullptr, h3);
        chi_kernel<<<NN / 256, 256, 0, stream>>>(h3, W4, b4, species, chi);
        charge_kernel<<<NMOL, NATOM, 0, stream>>>(chi, species, netq, q);
        esp_kernel<<<NMOL, NATOM, 0, stream>>>(coords, species, q, esp);
    }

    out_kernel<<<NN / 256, 256, 0, stream>>>(species, q, (float*)d_out);
}

// Round 3
// 588.760 us; speedup vs baseline: 3.1527x; 1.6152x over previous
//
#include <hip/hip_runtime.h>
#include <math.h>

#define NMOL 256
#define NATOM 384
#define NN (NMOL*NATOM)          // 98304
#define A0_INV (1.0f/0.529177249f)

typedef short bf16x8 __attribute__((ext_vector_type(8)));
typedef float f32x4  __attribute__((ext_vector_type(4)));

__constant__ float c_sigma[8] = {0.5515909f, 1.8886297f, 1.3225029f, 1.2316629f,
                                 2.1884933f, 1.7750372f, 1.3677907f, 1.3820058f};

__device__ __forceinline__ short f2b(float f) {           // f32 -> bf16 RNE
    unsigned u = __float_as_uint(f);
    u = (u + 0x7fffu + ((u >> 16) & 1u)) >> 16;
    return (short)u;
}
__device__ __forceinline__ float b2f(short s) {
    return __uint_as_float(((unsigned)(unsigned short)s) << 16);
}
__device__ __forceinline__ float celu01(float v) {
    return v > 0.f ? v : 0.1f * expm1f(10.f * v);
}
__device__ __forceinline__ bf16x8 cvt8(f32x4 a, f32x4 b) {
    bf16x8 r;
    r[0] = f2b(a.x); r[1] = f2b(a.y); r[2] = f2b(a.z); r[3] = f2b(a.w);
    r[4] = f2b(b.x); r[5] = f2b(b.y); r[6] = f2b(b.z); r[7] = f2b(b.w);
    return r;
}

// ======================= fused MFMA GEMM =======================
// BM=64 rows/block, 256 thr = 4 waves (2 row-halves x 2 col-halves)
// MODE 0: h1p = A(f32) @ B^T + bias              (no celu; A=aev)
// MODE 1: h2  = celu( celuA @ B^T + bias ),  celuA = celu(h1p + q*w1q + esp*w1e)
// MODE 2: chi = mask * softplus( celu(A @ B^T + bias) . W4 + b4 )   (A=h2; no C out)
template<int N, int K, int MODE>
__global__ __launch_bounds__(256, 4)
void gemm_k(const void* __restrict__ Aptr, const short* __restrict__ Bw,
            const float* __restrict__ bias,
            const float* __restrict__ qv, const float* __restrict__ espv,
            const float* __restrict__ w1qp, const float* __restrict__ w1ep,
            const float* __restrict__ W4, const float* __restrict__ b4,
            const int* __restrict__ species,
            short* __restrict__ Cout, float* __restrict__ chi)
{
    constexpr int NK = K / 32;
    constexpr int NF = N / 32;
    constexpr int N2 = N / 2;
    constexpr int AROW = 40, BROW = 40;       // padded LDS rows (bank-friendly)
    constexpr int ASZ = 64 * AROW;
    constexpr int BSZ = N * BROW;
    constexpr int AB  = 2 * ASZ + 2 * BSZ;
    constexpr int CSZ = 64 * N;
    constexpr int SM  = AB > CSZ ? AB : CSZ;
    constexpr int NB  = (N * 4 + 255) / 256;  // B 16-byte chunks per thread

    __shared__ short smem[SM];
    __shared__ float wq_s[MODE == 1 ? K : 1];
    __shared__ float we_s[MODE == 1 ? K : 1];
    __shared__ float w4_s[MODE == 2 ? 96 : 1];

    short* As0 = smem;
    short* As1 = smem + ASZ;
    short* Bs0 = smem + 2 * ASZ;
    short* Bs1 = smem + 2 * ASZ + BSZ;
    short* Cs  = smem;

    const int t    = threadIdx.x;
    const int lane = t & 63;
    const int wave = t >> 6;
    const int wm   = wave >> 1, wn = wave & 1;
    const int l15  = lane & 15, l4 = lane >> 4;
    const int m0   = blockIdx.x * 64;

    if (MODE == 1) { if (t < K) { wq_s[t] = w1qp[t]; we_s[t] = w1ep[t]; } }
    if (MODE == 2) { if (t < 96) w4_s[t] = W4[t]; }

    const int arow = t >> 2, aseg = t & 3;     // each thread: 8 A elems
    const size_t agrow = (size_t)m0 + arow;

    const float* a_f32 = (const float*)Aptr + agrow * K + aseg * 8;
    const short* a_b16 = (const short*)Aptr + agrow * K + aseg * 8;
    float qr = 0.f, er = 0.f;
    if (MODE == 1) { qr = qv[agrow]; er = espv[agrow]; }

    f32x4 af0, af1;
    bf16x8 ah;
    bf16x8 br[NB];

    auto loadA = [&](int k0) {
        if (MODE == 0) {
            af0 = *(const f32x4*)(a_f32 + k0);
            af1 = *(const f32x4*)(a_f32 + k0 + 4);
        } else {
            ah = *(const bf16x8*)(a_b16 + k0);
        }
    };
    auto loadB = [&](int k0) {
        #pragma unroll
        for (int ci = 0; ci < NB; ++ci) {
            int c = ci * 256 + t;
            if ((N * 4) % 256 == 0 || c < N * 4) {
                int row = c >> 2, half = c & 3;
                br[ci] = *(const bf16x8*)(Bw + (size_t)row * K + k0 + half * 8);
            }
        }
    };
    auto writeA = [&](short* dst, int k0) {
        bf16x8 o;
        if (MODE == 0) {
            o = cvt8(af0, af1);
        } else if (MODE == 1) {
            #pragma unroll
            for (int j = 0; j < 8; ++j) {
                float v = b2f(ah[j]) + qr * wq_s[k0 + aseg * 8 + j]
                                     + er * we_s[k0 + aseg * 8 + j];
                o[j] = f2b(celu01(v));
            }
        } else {
            o = ah;
        }
        *(bf16x8*)&dst[arow * AROW + aseg * 8] = o;
    };
    auto writeB = [&](short* dst) {
        #pragma unroll
        for (int ci = 0; ci < NB; ++ci) {
            int c = ci * 256 + t;
            if ((N * 4) % 256 == 0 || c < N * 4) {
                int row = c >> 2, half = c & 3;
                *(bf16x8*)&dst[row * BROW + half * 8] = br[ci];
            }
        }
    };

    f32x4 acc[2][NF] = {};

    __syncthreads();                 // wq_s/we_s visible before staging uses them
    loadA(0); loadB(0);
    writeA(As0, 0); writeB(Bs0);
    __syncthreads();

    int cur = 0;
    for (int ks = 0; ks < NK; ++ks) {
        if (ks + 1 < NK) { loadA((ks + 1) * 32); loadB((ks + 1) * 32); }
        short* Ac = cur ? As1 : As0;
        short* Bc = cur ? Bs1 : Bs0;
        bf16x8 a[2];
        #pragma unroll
        for (int mf = 0; mf < 2; ++mf)
            a[mf] = *(const bf16x8*)&Ac[(wm * 32 + mf * 16 + l15) * AROW + l4 * 8];
        #pragma unroll
        for (int nf = 0; nf < NF; ++nf) {
            bf16x8 b = *(const bf16x8*)&Bc[(wn * N2 + nf * 16 + l15) * BROW + l4 * 8];
            #pragma unroll
            for (int mf = 0; mf < 2; ++mf)
                acc[mf][nf] = __builtin_amdgcn_mfma_f32_16x16x32_bf16(a[mf], b, acc[mf][nf], 0, 0, 0);
        }
        if (ks + 1 < NK) {
            short* An = cur ? As0 : As1;
            short* Bn = cur ? Bs0 : Bs1;
            writeA(An, (ks + 1) * 32);
            writeB(Bn);
            __syncthreads();
            cur ^= 1;
        }
    }
    __syncthreads();   // all frag reads done before Cs (aliases As/Bs) is written

    // epilogue -> Cs (bf16)
    #pragma unroll
    for (int nf = 0; nf < NF; ++nf) {
        int col = wn * N2 + nf * 16 + l15;
        float bc = bias[col];
        #pragma unroll
        for (int mf = 0; mf < 2; ++mf)
            #pragma unroll
            for (int r = 0; r < 4; ++r) {
                float v = acc[mf][nf][r] + bc;
                if (MODE != 0) v = celu01(v);
                Cs[(wm * 32 + mf * 16 + l4 * 4 + r) * N + col] = f2b(v);
            }
    }
    __syncthreads();

    if (MODE != 2) {
        // coalesced bf16 store: Cs layout == global row-major layout
        #pragma unroll
        for (int i = 0; i < NF; ++i) {
            int c = i * 256 + t;
            *(bf16x8*)(Cout + (size_t)m0 * N + c * 8) = *(const bf16x8*)&Cs[c * 8];
        }
    } else {
        if (t < 64) {
            float s = 0.f;
            #pragma unroll
            for (int c = 0; c < 96; c += 8) {
                bf16x8 v = *(const bf16x8*)&Cs[t * 96 + c];
                #pragma unroll
                for (int j = 0; j < 8; ++j) s = fmaf(b2f(v[j]), w4_s[c + j], s);
            }
            s += b4[0];
            s = fmaxf(s, 0.f) + log1pf(expf(-fabsf(s)));   // softplus
            chi[m0 + t] = (species[m0 + t] != -1) ? s : 0.f;
        }
    }
}

// ============ fused charge normalization + ESP (one block per molecule) ============
template<bool DO_ESP>
__global__ __launch_bounds__(384)
void espq_kernel(const float* __restrict__ chi, const int* __restrict__ species,
                 const float* __restrict__ netq, const float* __restrict__ coords,
                 float* __restrict__ q, float* __restrict__ esp)
{
    __shared__ float red[512], redc[512];
    __shared__ float cx[NATOM], cy[NATOM], cz[NATOM], s2[NATOM], qs[NATOM];
    int m = blockIdx.x, j = threadIdx.x;
    int idx = m * NATOM + j;
    float c = chi[idx];
    int sp = species[idx];
    float mask = (sp != -1) ? 1.f : 0.f;
    red[j] = c; redc[j] = mask;
    if (j < 128) { red[NATOM + j] = 0.f; redc[NATOM + j] = 0.f; }
    __syncthreads();
    for (int s = 256; s > 0; s >>= 1) {
        if (j < s) { red[j] += red[j + s]; redc[j] += redc[j + s]; }
        __syncthreads();
    }
    float chi_sum = red[0], na = redc[0];
    float Q = netq[m];
    float k_net = 1.f + fabsf(Q) / chi_sum;
    float chi_mean = chi_sum / na;
    float k_p = (Q > 0.f) ? k_net : 1.f;
    float k_n = (Q < 0.f) ? k_net : 1.f;
    float qj = (-k_n * c + k_p * chi_mean) * mask;
    q[idx] = qj;

    if (DO_ESP) {
        float rx = coords[(size_t)idx * 3 + 0];
        float ry = coords[(size_t)idx * 3 + 1];
        float rz = coords[(size_t)idx * 3 + 2];
        cx[j] = rx; cy[j] = ry; cz[j] = rz;
        float sig = c_sigma[sp < 0 ? 7 : sp];
        s2[j] = sig * sig;
        qs[j] = qj;
        __syncthreads();
        float s2j = s2[j];
        float acc = 0.f;
        for (int i = 0; i < NATOM; ++i) {
            float dx = cx[i] - rx, dy = cy[i] - ry, dz = cz[i] - rz;
            float d2 = fmaf(dx, dx, fmaf(dy, dy, dz * dz)) + 1e-16f;
            float d = sqrtf(d2) * A0_INV;
            float ss = fmaxf(s2[i] + s2j, 1e-8f);
            float val = erff(d * rsqrtf(2.f * ss)) / d;
            acc += (i == j) ? 0.f : qs[i] * val;
        }
        esp[idx] = (mask != 0.f) ? acc : 0.f;
    }
}

// ============ one-time weight conversion to bf16 (+ rank-2 columns) ============
__global__ __launch_bounds__(256)
void wcvt_kernel(const float* __restrict__ W1, const float* __restrict__ W2,
                 const float* __restrict__ W3,
                 short* __restrict__ W1b, short* __restrict__ W2b,
                 short* __restrict__ W3b, float* __restrict__ w1q,
                 float* __restrict__ w1e)
{
    int i = blockIdx.x * 256 + threadIdx.x;
    if (i < 160 * 384) {
        int r = i / 384, cc = i % 384;
        W1b[i] = f2b(W1[(size_t)r * 386 + cc]);
    }
    int j = i - 160 * 384;
    if (j >= 0 && j < 128 * 160) W2b[j] = f2b(W2[j]);
    int k2 = j - 128 * 160;
    if (k2 >= 0 && k2 < 96 * 128) W3b[k2] = f2b(W3[k2]);
    if (i < 160) {
        w1q[i] = W1[(size_t)i * 386 + 384];
        w1e[i] = W1[(size_t)i * 386 + 385];
    }
}

// ---------------- output: [species as float | charges] ----------------
__global__ __launch_bounds__(256)
void out_kernel(const int* __restrict__ species, const float* __restrict__ q,
                float* __restrict__ out)
{
    int i = blockIdx.x * 256 + threadIdx.x;
    out[i] = (float)species[i];
    out[NN + i] = q[i];
}

extern "C" void kernel_launch(void* const* d_in, const int* in_sizes, int n_in,
                              void* d_out, int out_size, void* d_ws, size_t ws_size,
                              hipStream_t stream)
{
    const int*   species = (const int*)  d_in[0];
    const float* coords  = (const float*)d_in[1];
    const float* netq    = (const float*)d_in[2];
    const float* aev     = (const float*)d_in[3];
    const float* W1 = (const float*)d_in[4];
    const float* b1 = (const float*)d_in[5];
    const float* W2 = (const float*)d_in[6];
    const float* b2 = (const float*)d_in[7];
    const float* W3 = (const float*)d_in[8];
    const float* b3 = (const float*)d_in[9];
    const float* W4 = (const float*)d_in[10];
    const float* b4 = (const float*)d_in[11];

    float* q    = (float*)d_ws;                 // NN
    float* esp  = q + NN;                       // NN
    float* chi  = esp + NN;                     // NN
    float* w1q  = chi + NN;                     // 160
    float* w1e  = w1q + 160;                    // 160
    short* W1b  = (short*)(w1e + 160);          // 160*384
    short* W2b  = W1b + 160 * 384;              // 128*160
    short* W3b  = W2b + 128 * 160;              // 96*128
    short* h1p  = W3b + 96 * 128;               // NN*160 (pre-activation layer1 + b1)
    short* h2   = h1p + (size_t)NN * 160;       // NN*128

    hipMemsetAsync(q, 0, 2 * (size_t)NN * sizeof(float), stream);  // q = esp = 0
    wcvt_kernel<<<(160 * 384 + 128 * 160 + 96 * 128 + 255) / 256, 256, 0, stream>>>(
        W1, W2, W3, W1b, W2b, W3b, w1q, w1e);

    // iteration-invariant: h1p = aev @ W1[:, :384]^T + b1
    gemm_k<160, 384, 0><<<NN / 64, 256, 0, stream>>>(
        aev, W1b, b1, nullptr, nullptr, nullptr, nullptr, nullptr, nullptr, nullptr,
        h1p, nullptr);

    for (int it = 0; it < 4; ++it) {
        gemm_k<128, 160, 1><<<NN / 64, 256, 0, stream>>>(
            h1p, W2b, b2, q, esp, w1q, w1e, nullptr, nullptr, nullptr, h2, nullptr);
        gemm_k<96, 128, 2><<<NN / 64, 256, 0, stream>>>(
            h2, W3b, b3, nullptr, nullptr, nullptr, nullptr, W4, b4, species,
            nullptr, chi);
        if (it < 3)
            espq_kernel<true><<<NMOL, 384, 0, stream>>>(chi, species, netq, coords, q, esp);
        else
            espq_kernel<false><<<NMOL, 384, 0, stream>>>(chi, species, netq, coords, q, esp);
    }

    out_kernel<<<NN / 256, 256, 0, stream>>>(species, q, (float*)d_out);
}

// Round 4
// 360.387 us; speedup vs baseline: 5.1506x; 1.6337x over previous
//
#include <hip/hip_runtime.h>
#include <math.h>

#define NMOL 256
#define NATOM 384
#define NN (NMOL*NATOM)          // 98304
#define A0_INV (1.0f/0.529177249f)

typedef short bf16x8 __attribute__((ext_vector_type(8)));
typedef float f32x4  __attribute__((ext_vector_type(4)));
typedef _Float16 h16x8 __attribute__((ext_vector_type(8)));

__constant__ float c_sigma[8] = {0.5515909f, 1.8886297f, 1.3225029f, 1.2316629f,
                                 2.1884933f, 1.7750372f, 1.3677907f, 1.3820058f};

__device__ __forceinline__ short f2b(float f) {           // f32 -> bf16 RNE
    unsigned u = __float_as_uint(f);
    u = (u + 0x7fffu + ((u >> 16) & 1u)) >> 16;
    return (short)u;
}
__device__ __forceinline__ float b2f(short s) {
    return __uint_as_float(((unsigned)(unsigned short)s) << 16);
}
__device__ __forceinline__ float celu01(float v) {
    return v > 0.f ? v : 0.1f * expm1f(10.f * v);
}
__device__ __forceinline__ bf16x8 cvt8(f32x4 a, f32x4 b) {
    bf16x8 r;
    r[0] = f2b(a.x); r[1] = f2b(a.y); r[2] = f2b(a.z); r[3] = f2b(a.w);
    r[4] = f2b(b.x); r[5] = f2b(b.y); r[6] = f2b(b.z); r[7] = f2b(b.w);
    return r;
}

// ======================= fused MFMA GEMM =======================
// BM=64 rows/block, 256 thr = 4 waves (2 row-halves x 2 col-halves)
// MODE 0: h1p = A(f32) @ B^T + bias              (no celu; A=aev)
// MODE 1: h2  = celu( celuA @ B^T + bias ),  celuA = celu(h1p + q*w1q + esp*w1e)
//         esp feature = sum of 4 partial planes espv[k*NN + row]
// MODE 2: chi = mask * softplus( celu(A @ B^T + bias) . W4 + b4 )   (A=h2; no C out)
template<int N, int K, int MODE>
__global__ __launch_bounds__(256, 4)
void gemm_k(const void* __restrict__ Aptr, const short* __restrict__ Bw,
            const float* __restrict__ bias,
            const float* __restrict__ qv, const float* __restrict__ espv,
            const float* __restrict__ w1qp, const float* __restrict__ w1ep,
            const float* __restrict__ W4, const float* __restrict__ b4,
            const int* __restrict__ species,
            short* __restrict__ Cout, float* __restrict__ chi)
{
    constexpr int NK = K / 32;
    constexpr int NF = N / 32;
    constexpr int N2 = N / 2;
    constexpr int AROW = 40, BROW = 40;       // padded LDS rows (bank-friendly)
    constexpr int ASZ = 64 * AROW;
    constexpr int BSZ = N * BROW;
    constexpr int AB  = 2 * ASZ + 2 * BSZ;
    constexpr int CSZ = 64 * N;
    constexpr int SM  = AB > CSZ ? AB : CSZ;
    constexpr int NB  = (N * 4 + 255) / 256;  // B 16-byte chunks per thread

    __shared__ short smem[SM];
    __shared__ float wq_s[MODE == 1 ? K : 1];
    __shared__ float we_s[MODE == 1 ? K : 1];
    __shared__ float w4_s[MODE == 2 ? 96 : 1];

    short* As0 = smem;
    short* As1 = smem + ASZ;
    short* Bs0 = smem + 2 * ASZ;
    short* Bs1 = smem + 2 * ASZ + BSZ;
    short* Cs  = smem;

    const int t    = threadIdx.x;
    const int lane = t & 63;
    const int wave = t >> 6;
    const int wm   = wave >> 1, wn = wave & 1;
    const int l15  = lane & 15, l4 = lane >> 4;
    const int m0   = blockIdx.x * 64;

    if (MODE == 1) { if (t < K) { wq_s[t] = w1qp[t]; we_s[t] = w1ep[t]; } }
    if (MODE == 2) { if (t < 96) w4_s[t] = W4[t]; }

    const int arow = t >> 2, aseg = t & 3;     // each thread: 8 A elems
    const size_t agrow = (size_t)m0 + arow;

    const float* a_f32 = (const float*)Aptr + agrow * K + aseg * 8;
    const short* a_b16 = (const short*)Aptr + agrow * K + aseg * 8;
    float qr = 0.f, er = 0.f;
    if (MODE == 1) {
        qr = qv[agrow];
        er = espv[agrow] + espv[NN + agrow] + espv[2 * (size_t)NN + agrow]
           + espv[3 * (size_t)NN + agrow];
    }

    f32x4 af0, af1;
    bf16x8 ah;
    bf16x8 br[NB];

    auto loadA = [&](int k0) {
        if (MODE == 0) {
            af0 = *(const f32x4*)(a_f32 + k0);
            af1 = *(const f32x4*)(a_f32 + k0 + 4);
        } else {
            ah = *(const bf16x8*)(a_b16 + k0);
        }
    };
    auto loadB = [&](int k0) {
        #pragma unroll
        for (int ci = 0; ci < NB; ++ci) {
            int c = ci * 256 + t;
            if ((N * 4) % 256 == 0 || c < N * 4) {
                int row = c >> 2, half = c & 3;
                br[ci] = *(const bf16x8*)(Bw + (size_t)row * K + k0 + half * 8);
            }
        }
    };
    auto writeA = [&](short* dst, int k0) {
        bf16x8 o;
        if (MODE == 0) {
            o = cvt8(af0, af1);
        } else if (MODE == 1) {
            #pragma unroll
            for (int j = 0; j < 8; ++j) {
                float v = b2f(ah[j]) + qr * wq_s[k0 + aseg * 8 + j]
                                     + er * we_s[k0 + aseg * 8 + j];
                o[j] = f2b(celu01(v));
            }
        } else {
            o = ah;
        }
        *(bf16x8*)&dst[arow * AROW + aseg * 8] = o;
    };
    auto writeB = [&](short* dst) {
        #pragma unroll
        for (int ci = 0; ci < NB; ++ci) {
            int c = ci * 256 + t;
            if ((N * 4) % 256 == 0 || c < N * 4) {
                int row = c >> 2, half = c & 3;
                *(bf16x8*)&dst[row * BROW + half * 8] = br[ci];
            }
        }
    };

    f32x4 acc[2][NF] = {};

    __syncthreads();                 // wq_s/we_s visible before staging uses them
    loadA(0); loadB(0);
    writeA(As0, 0); writeB(Bs0);
    __syncthreads();

    int cur = 0;
    for (int ks = 0; ks < NK; ++ks) {
        if (ks + 1 < NK) { loadA((ks + 1) * 32); loadB((ks + 1) * 32); }
        short* Ac = cur ? As1 : As0;
        short* Bc = cur ? Bs1 : Bs0;
        bf16x8 a[2];
        #pragma unroll
        for (int mf = 0; mf < 2; ++mf)
            a[mf] = *(const bf16x8*)&Ac[(wm * 32 + mf * 16 + l15) * AROW + l4 * 8];
        #pragma unroll
        for (int nf = 0; nf < NF; ++nf) {
            bf16x8 b = *(const bf16x8*)&Bc[(wn * N2 + nf * 16 + l15) * BROW + l4 * 8];
            #pragma unroll
            for (int mf = 0; mf < 2; ++mf)
                acc[mf][nf] = __builtin_amdgcn_mfma_f32_16x16x32_bf16(a[mf], b, acc[mf][nf], 0, 0, 0);
        }
        if (ks + 1 < NK) {
            short* An = cur ? As0 : As1;
            short* Bn = cur ? Bs0 : Bs1;
            writeA(An, (ks + 1) * 32);
            writeB(Bn);
            __syncthreads();
            cur ^= 1;
        }
    }
    __syncthreads();   // all frag reads done before Cs (aliases As/Bs) is written

    // epilogue -> Cs (bf16)
    #pragma unroll
    for (int nf = 0; nf < NF; ++nf) {
        int col = wn * N2 + nf * 16 + l15;
        float bc = bias[col];
        #pragma unroll
        for (int mf = 0; mf < 2; ++mf)
            #pragma unroll
            for (int r = 0; r < 4; ++r) {
                float v = acc[mf][nf][r] + bc;
                if (MODE != 0) v = celu01(v);
                Cs[(wm * 32 + mf * 16 + l4 * 4 + r) * N + col] = f2b(v);
            }
    }
    __syncthreads();

    if (MODE != 2) {
        // coalesced bf16 store: Cs layout == global row-major layout
        #pragma unroll
        for (int i = 0; i < NF; ++i) {
            int c = i * 256 + t;
            *(bf16x8*)(Cout + (size_t)m0 * N + c * 8) = *(const bf16x8*)&Cs[c * 8];
        }
    } else {
        if (t < 64) {
            float s = 0.f;
            #pragma unroll
            for (int c = 0; c < 96; c += 8) {
                bf16x8 v = *(const bf16x8*)&Cs[t * 96 + c];
                #pragma unroll
                for (int j = 0; j < 8; ++j) s = fmaf(b2f(v[j]), w4_s[c + j], s);
            }
            s += b4[0];
            s = fmaxf(s, 0.f) + log1pf(expf(-fabsf(s)));   // softplus
            chi[m0 + t] = (species[m0 + t] != -1) ? s : 0.f;
        }
    }
}

// ============ J-matrix build (iteration-invariant), fp16, masked ============
// grid (NMOL, 8 i-tiles of 48), block 384 (j)
__global__ __launch_bounds__(384)
void jbuild_kernel(const float* __restrict__ coords, const int* __restrict__ species,
                   _Float16* __restrict__ J)
{
    __shared__ float cx[NATOM], cy[NATOM], cz[NATOM], s2[NATOM], mk[NATOM];
    int m = blockIdx.x, it0 = blockIdx.y * 48;
    int j = threadIdx.x;
    int idx = m * NATOM + j;
    float rx = coords[(size_t)idx * 3 + 0];
    float ry = coords[(size_t)idx * 3 + 1];
    float rz = coords[(size_t)idx * 3 + 2];
    int sp = species[idx];
    float sig = c_sigma[sp < 0 ? 7 : sp];
    cx[j] = rx; cy[j] = ry; cz[j] = rz;
    s2[j] = sig * sig;
    float maskj = (sp != -1) ? 1.f : 0.f;
    mk[j] = maskj;
    __syncthreads();
    float s2j = s2[j];
    #pragma unroll 4
    for (int ii = 0; ii < 48; ++ii) {
        int i = it0 + ii;
        float dx = cx[i] - rx, dy = cy[i] - ry, dz = cz[i] - rz;
        float d2 = fmaf(dx, dx, fmaf(dy, dy, dz * dz)) + 1e-16f;
        float d = sqrtf(d2) * A0_INV;
        float ss = fmaxf(s2[i] + s2j, 1e-8f);
        float val = erff(d * rsqrtf(2.f * ss)) / d * maskj * mk[i];
        val = (i == j) ? 0.f : val;
        J[((size_t)m * NATOM + i) * NATOM + j] = (_Float16)val;
    }
}

// ============ fused charge normalization + ESP matvec partials ============
// grid (NMOL, DO_MV?4:1), block 384.  esp_part[ic][m][j] = sum_{i in chunk ic} q_i J[i][j]
template<bool DO_MV>
__global__ __launch_bounds__(384)
void espmv_kernel(const float* __restrict__ chi, const int* __restrict__ species,
                  const float* __restrict__ netq, const _Float16* __restrict__ J,
                  float* __restrict__ q, float* __restrict__ esp_part)
{
    __shared__ float red[512], redc[512];
    __shared__ float qs[DO_MV ? 96 : 1];
    __shared__ float part[DO_MV ? 8 : 1][DO_MV ? 384 : 1];
    int m = blockIdx.x, ic = blockIdx.y;
    int t = threadIdx.x;
    int idx = m * NATOM + t;
    float c = chi[idx];
    int sp = species[idx];
    float mask = (sp != -1) ? 1.f : 0.f;
    red[t] = c; redc[t] = mask;
    if (t < 128) { red[NATOM + t] = 0.f; redc[NATOM + t] = 0.f; }
    __syncthreads();
    for (int s = 256; s > 0; s >>= 1) {
        if (t < s) { red[t] += red[t + s]; redc[t] += redc[t + s]; }
        __syncthreads();
    }
    float chi_sum = red[0], na = redc[0];
    float Q = netq[m];
    float k_net = 1.f + fabsf(Q) / chi_sum;
    float chi_mean = chi_sum / na;
    float k_p = (Q > 0.f) ? k_net : 1.f;
    float k_n = (Q < 0.f) ? k_net : 1.f;
    float qj = (-k_n * c + k_p * chi_mean) * mask;
    if (ic == 0) q[idx] = qj;

    if (DO_MV) {
        if (t >= ic * 96 && t < ic * 96 + 96) qs[t - ic * 96] = qj;
        __syncthreads();
        int jv = t % 48, isub = t / 48;
        int j0 = jv * 8;
        float acc[8] = {};
        #pragma unroll 4
        for (int k = 0; k < 12; ++k) {
            int il = isub * 12 + k;
            int i = ic * 96 + il;
            h16x8 h = *(const h16x8*)&J[((size_t)m * NATOM + i) * NATOM + j0];
            float qi = qs[il];
            #pragma unroll
            for (int r = 0; r < 8; ++r) acc[r] = fmaf(qi, (float)h[r], acc[r]);
        }
        #pragma unroll
        for (int r = 0; r < 8; ++r) part[isub][j0 + r] = acc[r];
        __syncthreads();
        float s = 0.f;
        #pragma unroll
        for (int g = 0; g < 8; ++g) s += part[g][t];
        esp_part[(size_t)ic * NN + idx] = s;
    }
}

// ============ fallback: direct charge+ESP (ws too small for J) ============
template<bool DO_ESP>
__global__ __launch_bounds__(384)
void espq_kernel(const float* __restrict__ chi, const int* __restrict__ species,
                 const float* __restrict__ netq, const float* __restrict__ coords,
                 float* __restrict__ q, float* __restrict__ esp)
{
    __shared__ float red[512], redc[512];
    __shared__ float cx[NATOM], cy[NATOM], cz[NATOM], s2[NATOM], qs[NATOM];
    int m = blockIdx.x, j = threadIdx.x;
    int idx = m * NATOM + j;
    float c = chi[idx];
    int sp = species[idx];
    float mask = (sp != -1) ? 1.f : 0.f;
    red[j] = c; redc[j] = mask;
    if (j < 128) { red[NATOM + j] = 0.f; redc[NATOM + j] = 0.f; }
    __syncthreads();
    for (int s = 256; s > 0; s >>= 1) {
        if (j < s) { red[j] += red[j + s]; redc[j] += redc[j + s]; }
        __syncthreads();
    }
    float chi_sum = red[0], na = redc[0];
    float Q = netq[m];
    float k_net = 1.f + fabsf(Q) / chi_sum;
    float chi_mean = chi_sum / na;
    float k_p = (Q > 0.f) ? k_net : 1.f;
    float k_n = (Q < 0.f) ? k_net : 1.f;
    float qj = (-k_n * c + k_p * chi_mean) * mask;
    q[idx] = qj;

    if (DO_ESP) {
        float rx = coords[(size_t)idx * 3 + 0];
        float ry = coords[(size_t)idx * 3 + 1];
        float rz = coords[(size_t)idx * 3 + 2];
        cx[j] = rx; cy[j] = ry; cz[j] = rz;
        float sig = c_sigma[sp < 0 ? 7 : sp];
        s2[j] = sig * sig;
        qs[j] = qj;
        __syncthreads();
        float s2j = s2[j];
        float acc = 0.f;
        for (int i = 0; i < NATOM; ++i) {
            float dx = cx[i] - rx, dy = cy[i] - ry, dz = cz[i] - rz;
            float d2 = fmaf(dx, dx, fmaf(dy, dy, dz * dz)) + 1e-16f;
            float d = sqrtf(d2) * A0_INV;
            float ss = fmaxf(s2[i] + s2j, 1e-8f);
            float val = erff(d * rsqrtf(2.f * ss)) / d;
            acc += (i == j) ? 0.f : qs[i] * val;
        }
        esp[idx] = (mask != 0.f) ? acc : 0.f;
    }
}

// ============ one-time weight conversion to bf16 (+ rank-2 columns) ============
__global__ __launch_bounds__(256)
void wcvt_kernel(const float* __restrict__ W1, const float* __restrict__ W2,
                 const float* __restrict__ W3,
                 short* __restrict__ W1b, short* __restrict__ W2b,
                 short* __restrict__ W3b, float* __restrict__ w1q,
                 float* __restrict__ w1e)
{
    int i = blockIdx.x * 256 + threadIdx.x;
    if (i < 160 * 384) {
        int r = i / 384, cc = i % 384;
        W1b[i] = f2b(W1[(size_t)r * 386 + cc]);
    }
    int j = i - 160 * 384;
    if (j >= 0 && j < 128 * 160) W2b[j] = f2b(W2[j]);
    int k2 = j - 128 * 160;
    if (k2 >= 0 && k2 < 96 * 128) W3b[k2] = f2b(W3[k2]);
    if (i < 160) {
        w1q[i] = W1[(size_t)i * 386 + 384];
        w1e[i] = W1[(size_t)i * 386 + 385];
    }
}

// ---------------- output: [species as float | charges] ----------------
__global__ __launch_bounds__(256)
void out_kernel(const int* __restrict__ species, const float* __restrict__ q,
                float* __restrict__ out)
{
    int i = blockIdx.x * 256 + threadIdx.x;
    out[i] = (float)species[i];
    out[NN + i] = q[i];
}

extern "C" void kernel_launch(void* const* d_in, const int* in_sizes, int n_in,
                              void* d_out, int out_size, void* d_ws, size_t ws_size,
                              hipStream_t stream)
{
    const int*   species = (const int*)  d_in[0];
    const float* coords  = (const float*)d_in[1];
    const float* netq    = (const float*)d_in[2];
    const float* aev     = (const float*)d_in[3];
    const float* W1 = (const float*)d_in[4];
    const float* b1 = (const float*)d_in[5];
    const float* W2 = (const float*)d_in[6];
    const float* b2 = (const float*)d_in[7];
    const float* W3 = (const float*)d_in[8];
    const float* b3 = (const float*)d_in[9];
    const float* W4 = (const float*)d_in[10];
    const float* b4 = (const float*)d_in[11];

    float* q    = (float*)d_ws;                 // NN
    float* chi  = q + NN;                       // NN
    float* espp = chi + NN;                     // 4*NN partial planes
    float* w1q  = espp + 4 * (size_t)NN;        // 160
    float* w1e  = w1q + 160;                    // 160
    short* W1b  = (short*)(w1e + 160);          // 160*384
    short* W2b  = W1b + 160 * 384;              // 128*160
    short* W3b  = W2b + 128 * 160;              // 96*128
    short* h1p  = W3b + 96 * 128;               // NN*160 bf16
    short* h2   = h1p + (size_t)NN * 160;       // NN*128 bf16
    _Float16* J = (_Float16*)(h2 + (size_t)NN * 128);   // NN*384 fp16

    const size_t NEED = (size_t)((char*)(J + (size_t)NN * 384) - (char*)d_ws);
    const bool use_J = (ws_size >= NEED);

    // zero q + espp planes (iteration-0 features; unused planes stay 0 in fallback)
    hipMemsetAsync(d_ws, 0, 6 * (size_t)NN * sizeof(float), stream);
    wcvt_kernel<<<(160 * 384 + 128 * 160 + 96 * 128 + 255) / 256, 256, 0, stream>>>(
        W1, W2, W3, W1b, W2b, W3b, w1q, w1e);

    if (use_J)
        jbuild_kernel<<<dim3(NMOL, 8), 384, 0, stream>>>(coords, species, J);

    // iteration-invariant: h1p = aev @ W1[:, :384]^T + b1
    gemm_k<160, 384, 0><<<NN / 64, 256, 0, stream>>>(
        aev, W1b, b1, nullptr, nullptr, nullptr, nullptr, nullptr, nullptr, nullptr,
        h1p, nullptr);

    for (int it = 0; it < 4; ++it) {
        gemm_k<128, 160, 1><<<NN / 64, 256, 0, stream>>>(
            h1p, W2b, b2, q, espp, w1q, w1e, nullptr, nullptr, nullptr, h2, nullptr);
        gemm_k<96, 128, 2><<<NN / 64, 256, 0, stream>>>(
            h2, W3b, b3, nullptr, nullptr, nullptr, nullptr, W4, b4, species,
            nullptr, chi);
        if (use_J) {
            if (it < 3)
                espmv_kernel<true><<<dim3(NMOL, 4), 384, 0, stream>>>(
                    chi, species, netq, J, q, espp);
            else
                espmv_kernel<false><<<dim3(NMOL, 1), 384, 0, stream>>>(
                    chi, species, netq, J, q, espp);
        } else {
            if (it < 3)
                espq_kernel<true><<<NMOL, 384, 0, stream>>>(
                    chi, species, netq, coords, q, espp);
            else
                espq_kernel<false><<<NMOL, 384, 0, stream>>>(
                    chi, species, netq, coords, q, espp);
        }
    }

    out_kernel<<<NN / 256, 256, 0, stream>>>(species, q, (float*)d_out);
}

// Round 5
// 328.225 us; speedup vs baseline: 5.6553x; 1.0980x over previous
//
#include <hip/hip_runtime.h>
#include <math.h>

#define NMOL 256
#define NATOM 384
#define NN (NMOL*NATOM)          // 98304
#define A0C  0.529177249f
#define A0_INV (1.0f/0.529177249f)

typedef short bf16x8 __attribute__((ext_vector_type(8)));
typedef float f32x4  __attribute__((ext_vector_type(4)));
typedef _Float16 h16x8 __attribute__((ext_vector_type(8)));

__constant__ float c_sigma[8] = {0.5515909f, 1.8886297f, 1.3225029f, 1.2316629f,
                                 2.1884933f, 1.7750372f, 1.3677907f, 1.3820058f};

__device__ __forceinline__ short f2b(float f) {           // f32 -> bf16 RNE
    unsigned u = __float_as_uint(f);
    u = (u + 0x7fffu + ((u >> 16) & 1u)) >> 16;
    return (short)u;
}
__device__ __forceinline__ float b2f(short s) {
    return __uint_as_float(((unsigned)(unsigned short)s) << 16);
}
__device__ __forceinline__ float celu01(float v) {
    return v > 0.f ? v : 0.1f * expm1f(10.f * v);
}
__device__ __forceinline__ bf16x8 cvt8(f32x4 a, f32x4 b) {
    bf16x8 r;
    r[0] = f2b(a.x); r[1] = f2b(a.y); r[2] = f2b(a.z); r[3] = f2b(a.w);
    r[4] = f2b(b.x); r[5] = f2b(b.y); r[6] = f2b(b.z); r[7] = f2b(b.w);
    return r;
}

// fast erf (x>=0): Abramowitz-Stegun 7.1.26, |abs err| <= 1.5e-7
__device__ __forceinline__ float erf_fast(float x) {
    float t = __builtin_amdgcn_rcpf(fmaf(0.3275911f, x, 1.0f));
    float p = fmaf(t, 1.061405429f, -1.453152027f);
    p = fmaf(t, p, 1.421413741f);
    p = fmaf(t, p, -0.284496736f);
    p = fmaf(t, p, 0.254829592f);
    p = p * t;
    float e = __builtin_amdgcn_exp2f(-x * x * 1.4426950408889634f);
    return fmaf(-p, e, 1.0f);
}

// ======================= fused MFMA GEMM =======================
// BM=64 rows/block, 256 thr = 4 waves (2 row-halves x 2 col-halves)
// MODE 0: h1p = A(f32) @ B^T + bias              (no celu; A=aev)
// MODE 1: h2  = celu( celuA @ B^T + bias ),  celuA = celu(h1p + q*w1q + esp*w1e)
//         esp feature = sum of 4 partial planes espv[k*NN + row]
// MODE 2: chi = mask * softplus( celu(A @ B^T + bias) . W4 + b4 )   (A=h2; no C out)
template<int N, int K, int MODE>
__global__ __launch_bounds__(256, 4)
void gemm_k(const void* __restrict__ Aptr, const short* __restrict__ Bw,
            const float* __restrict__ bias,
            const float* __restrict__ qv, const float* __restrict__ espv,
            const float* __restrict__ w1qp, const float* __restrict__ w1ep,
            const float* __restrict__ W4, const float* __restrict__ b4,
            const int* __restrict__ species,
            short* __restrict__ Cout, float* __restrict__ chi)
{
    constexpr int NK = K / 32;
    constexpr int NF = N / 32;
    constexpr int N2 = N / 2;
    constexpr int AROW = 40, BROW = 40;       // padded LDS rows (bank-friendly)
    constexpr int ASZ = 64 * AROW;
    constexpr int BSZ = N * BROW;
    constexpr int AB  = 2 * ASZ + 2 * BSZ;
    constexpr int CSZ = 64 * N;
    constexpr int SM  = AB > CSZ ? AB : CSZ;
    constexpr int NB  = (N * 4 + 255) / 256;  // B 16-byte chunks per thread

    __shared__ short smem[SM];
    __shared__ float wq_s[MODE == 1 ? K : 1];
    __shared__ float we_s[MODE == 1 ? K : 1];
    __shared__ float w4_s[MODE == 2 ? 96 : 1];

    short* As0 = smem;
    short* As1 = smem + ASZ;
    short* Bs0 = smem + 2 * ASZ;
    short* Bs1 = smem + 2 * ASZ + BSZ;
    short* Cs  = smem;

    const int t    = threadIdx.x;
    const int lane = t & 63;
    const int wave = t >> 6;
    const int wm   = wave >> 1, wn = wave & 1;
    const int l15  = lane & 15, l4 = lane >> 4;
    const int m0   = blockIdx.x * 64;

    if (MODE == 1) { if (t < K) { wq_s[t] = w1qp[t]; we_s[t] = w1ep[t]; } }
    if (MODE == 2) { if (t < 96) w4_s[t] = W4[t]; }

    const int arow = t >> 2, aseg = t & 3;     // each thread: 8 A elems
    const size_t agrow = (size_t)m0 + arow;

    const float* a_f32 = (const float*)Aptr + agrow * K + aseg * 8;
    const short* a_b16 = (const short*)Aptr + agrow * K + aseg * 8;
    float qr = 0.f, er = 0.f;
    if (MODE == 1) {
        qr = qv[agrow];
        er = espv[agrow] + espv[NN + agrow] + espv[2 * (size_t)NN + agrow]
           + espv[3 * (size_t)NN + agrow];
    }

    f32x4 af0, af1;
    bf16x8 ah;
    bf16x8 br[NB];

    auto loadA = [&](int k0) {
        if (MODE == 0) {
            af0 = *(const f32x4*)(a_f32 + k0);
            af1 = *(const f32x4*)(a_f32 + k0 + 4);
        } else {
            ah = *(const bf16x8*)(a_b16 + k0);
        }
    };
    auto loadB = [&](int k0) {
        #pragma unroll
        for (int ci = 0; ci < NB; ++ci) {
            int c = ci * 256 + t;
            if ((N * 4) % 256 == 0 || c < N * 4) {
                int row = c >> 2, half = c & 3;
                br[ci] = *(const bf16x8*)(Bw + (size_t)row * K + k0 + half * 8);
            }
        }
    };
    auto writeA = [&](short* dst, int k0) {
        bf16x8 o;
        if (MODE == 0) {
            o = cvt8(af0, af1);
        } else if (MODE == 1) {
            #pragma unroll
            for (int j = 0; j < 8; ++j) {
                float v = b2f(ah[j]) + qr * wq_s[k0 + aseg * 8 + j]
                                     + er * we_s[k0 + aseg * 8 + j];
                o[j] = f2b(celu01(v));
            }
        } else {
            o = ah;
        }
        *(bf16x8*)&dst[arow * AROW + aseg * 8] = o;
    };
    auto writeB = [&](short* dst) {
        #pragma unroll
        for (int ci = 0; ci < NB; ++ci) {
            int c = ci * 256 + t;
            if ((N * 4) % 256 == 0 || c < N * 4) {
                int row = c >> 2, half = c & 3;
                *(bf16x8*)&dst[row * BROW + half * 8] = br[ci];
            }
        }
    };

    f32x4 acc[2][NF] = {};

    __syncthreads();                 // wq_s/we_s visible before staging uses them
    loadA(0); loadB(0);
    writeA(As0, 0); writeB(Bs0);
    __syncthreads();

    int cur = 0;
    for (int ks = 0; ks < NK; ++ks) {
        if (ks + 1 < NK) { loadA((ks + 1) * 32); loadB((ks + 1) * 32); }
        short* Ac = cur ? As1 : As0;
        short* Bc = cur ? Bs1 : Bs0;
        bf16x8 a[2];
        #pragma unroll
        for (int mf = 0; mf < 2; ++mf)
            a[mf] = *(const bf16x8*)&Ac[(wm * 32 + mf * 16 + l15) * AROW + l4 * 8];
        #pragma unroll
        for (int nf = 0; nf < NF; ++nf) {
            bf16x8 b = *(const bf16x8*)&Bc[(wn * N2 + nf * 16 + l15) * BROW + l4 * 8];
            #pragma unroll
            for (int mf = 0; mf < 2; ++mf)
                acc[mf][nf] = __builtin_amdgcn_mfma_f32_16x16x32_bf16(a[mf], b, acc[mf][nf], 0, 0, 0);
        }
        if (ks + 1 < NK) {
            short* An = cur ? As0 : As1;
            short* Bn = cur ? Bs0 : Bs1;
            writeA(An, (ks + 1) * 32);
            writeB(Bn);
            __syncthreads();
            cur ^= 1;
        }
    }
    __syncthreads();   // all frag reads done before Cs (aliases As/Bs) is written

    // epilogue -> Cs (bf16)
    #pragma unroll
    for (int nf = 0; nf < NF; ++nf) {
        int col = wn * N2 + nf * 16 + l15;
        float bc = bias[col];
        #pragma unroll
        for (int mf = 0; mf < 2; ++mf)
            #pragma unroll
            for (int r = 0; r < 4; ++r) {
                float v = acc[mf][nf][r] + bc;
                if (MODE != 0) v = celu01(v);
                Cs[(wm * 32 + mf * 16 + l4 * 4 + r) * N + col] = f2b(v);
            }
    }
    __syncthreads();

    if (MODE != 2) {
        // coalesced bf16 store: Cs layout == global row-major layout
        #pragma unroll
        for (int i = 0; i < NF; ++i) {
            int c = i * 256 + t;
            *(bf16x8*)(Cout + (size_t)m0 * N + c * 8) = *(const bf16x8*)&Cs[c * 8];
        }
    } else {
        if (t < 64) {
            float s = 0.f;
            #pragma unroll
            for (int c = 0; c < 96; c += 8) {
                bf16x8 v = *(const bf16x8*)&Cs[t * 96 + c];
                #pragma unroll
                for (int j = 0; j < 8; ++j) s = fmaf(b2f(v[j]), w4_s[c + j], s);
            }
            s += b4[0];
            s = fmaxf(s, 0.f) + log1pf(expf(-fabsf(s)));   // softplus
            chi[m0 + t] = (species[m0 + t] != -1) ? s : 0.f;
        }
    }
}

// ============ J-matrix build (iteration-invariant), fp16, masked ============
// grid (NMOL, 8 i-tiles of 48), block 384 (j).  Uses fast erf + rsq (no div/sqrt).
__global__ __launch_bounds__(384)
void jbuild_kernel(const float* __restrict__ coords, const int* __restrict__ species,
                   _Float16* __restrict__ J)
{
    __shared__ float cx[NATOM], cy[NATOM], cz[NATOM], s2[NATOM], mk[NATOM];
    int m = blockIdx.x, it0 = blockIdx.y * 48;
    int j = threadIdx.x;
    int idx = m * NATOM + j;
    float rx = coords[(size_t)idx * 3 + 0];
    float ry = coords[(size_t)idx * 3 + 1];
    float rz = coords[(size_t)idx * 3 + 2];
    int sp = species[idx];
    float sig = c_sigma[sp < 0 ? 7 : sp];
    cx[j] = rx; cy[j] = ry; cz[j] = rz;
    s2[j] = sig * sig;
    float maskj = (sp != -1) ? 1.f : 0.f;
    mk[j] = maskj;
    __syncthreads();
    float s2j = s2[j];
    #pragma unroll 4
    for (int ii = 0; ii < 48; ++ii) {
        int i = it0 + ii;
        float dx = cx[i] - rx, dy = cy[i] - ry, dz = cz[i] - rz;
        float d2 = fmaf(dx, dx, fmaf(dy, dy, dz * dz)) + 1e-16f;
        float rs = __builtin_amdgcn_rsqf(d2);           // 1/sqrt(d2)
        float d  = d2 * rs * A0_INV;                    // |r|/A0 (Bohr)
        float ss = fmaxf(s2[i] + s2j, 1e-8f);
        float x  = d * __builtin_amdgcn_rsqf(2.f * ss);
        float val = erf_fast(x) * rs * A0C;             // erf(x)/d
        val *= maskj * mk[i];
        val = (i == j) ? 0.f : val;
        J[((size_t)m * NATOM + i) * NATOM + j] = (_Float16)val;
    }
}

// ============ fused charge normalization + ESP matvec partials ============
// grid (NMOL, DO_MV?4:1), block 384.  esp_part[ic][m][j] = sum_{i in chunk ic} q_i J[i][j]
template<bool DO_MV>
__global__ __launch_bounds__(384)
void espmv_kernel(const float* __restrict__ chi, const int* __restrict__ species,
                  const float* __restrict__ netq, const _Float16* __restrict__ J,
                  float* __restrict__ q, float* __restrict__ esp_part)
{
    __shared__ float red[512], redc[512];
    __shared__ float qs[DO_MV ? 96 : 1];
    __shared__ float part[DO_MV ? 8 : 1][DO_MV ? 384 : 1];
    int m = blockIdx.x, ic = blockIdx.y;
    int t = threadIdx.x;
    int idx = m * NATOM + t;
    float c = chi[idx];
    int sp = species[idx];
    float mask = (sp != -1) ? 1.f : 0.f;
    red[t] = c; redc[t] = mask;
    if (t < 128) { red[NATOM + t] = 0.f; redc[NATOM + t] = 0.f; }
    __syncthreads();
    for (int s = 256; s > 0; s >>= 1) {
        if (t < s) { red[t] += red[t + s]; redc[t] += redc[t + s]; }
        __syncthreads();
    }
    float chi_sum = red[0], na = redc[0];
    float Q = netq[m];
    float k_net = 1.f + fabsf(Q) / chi_sum;
    float chi_mean = chi_sum / na;
    float k_p = (Q > 0.f) ? k_net : 1.f;
    float k_n = (Q < 0.f) ? k_net : 1.f;
    float qj = (-k_n * c + k_p * chi_mean) * mask;
    if (ic == 0) q[idx] = qj;

    if (DO_MV) {
        if (t >= ic * 96 && t < ic * 96 + 96) qs[t - ic * 96] = qj;
        __syncthreads();
        int jv = t % 48, isub = t / 48;
        int j0 = jv * 8;
        float acc[8] = {};
        #pragma unroll 4
        for (int k = 0; k < 12; ++k) {
            int il = isub * 12 + k;
            int i = ic * 96 + il;
            h16x8 h = *(const h16x8*)&J[((size_t)m * NATOM + i) * NATOM + j0];
            float qi = qs[il];
            #pragma unroll
            for (int r = 0; r < 8; ++r) acc[r] = fmaf(qi, (float)h[r], acc[r]);
        }
        #pragma unroll
        for (int r = 0; r < 8; ++r) part[isub][j0 + r] = acc[r];
        __syncthreads();
        float s = 0.f;
        #pragma unroll
        for (int g = 0; g < 8; ++g) s += part[g][t];
        esp_part[(size_t)ic * NN + idx] = s;
    }
}

// ============ fallback: direct charge+ESP (ws too small for J) ============
template<bool DO_ESP>
__global__ __launch_bounds__(384)
void espq_kernel(const float* __restrict__ chi, const int* __restrict__ species,
                 const float* __restrict__ netq, const float* __restrict__ coords,
                 float* __restrict__ q, float* __restrict__ esp)
{
    __shared__ float red[512], redc[512];
    __shared__ float cx[NATOM], cy[NATOM], cz[NATOM], s2[NATOM], qs[NATOM];
    int m = blockIdx.x, j = threadIdx.x;
    int idx = m * NATOM + j;
    float c = chi[idx];
    int sp = species[idx];
    float mask = (sp != -1) ? 1.f : 0.f;
    red[j] = c; redc[j] = mask;
    if (j < 128) { red[NATOM + j] = 0.f; redc[NATOM + j] = 0.f; }
    __syncthreads();
    for (int s = 256; s > 0; s >>= 1) {
        if (j < s) { red[j] += red[j + s]; redc[j] += redc[j + s]; }
        __syncthreads();
    }
    float chi_sum = red[0], na = redc[0];
    float Q = netq[m];
    float k_net = 1.f + fabsf(Q) / chi_sum;
    float chi_mean = chi_sum / na;
    float k_p = (Q > 0.f) ? k_net : 1.f;
    float k_n = (Q < 0.f) ? k_net : 1.f;
    float qj = (-k_n * c + k_p * chi_mean) * mask;
    q[idx] = qj;

    if (DO_ESP) {
        float rx = coords[(size_t)idx * 3 + 0];
        float ry = coords[(size_t)idx * 3 + 1];
        float rz = coords[(size_t)idx * 3 + 2];
        cx[j] = rx; cy[j] = ry; cz[j] = rz;
        float sig = c_sigma[sp < 0 ? 7 : sp];
        s2[j] = sig * sig;
        qs[j] = qj;
        __syncthreads();
        float s2j = s2[j];
        float acc = 0.f;
        for (int i = 0; i < NATOM; ++i) {
            float dx = cx[i] - rx, dy = cy[i] - ry, dz = cz[i] - rz;
            float d2 = fmaf(dx, dx, fmaf(dy, dy, dz * dz)) + 1e-16f;
            float rs = __builtin_amdgcn_rsqf(d2);
            float d  = d2 * rs * A0_INV;
            float ss = fmaxf(s2[i] + s2j, 1e-8f);
            float x  = d * __builtin_amdgcn_rsqf(2.f * ss);
            float val = erf_fast(x) * rs * A0C;
            acc += (i == j) ? 0.f : qs[i] * val;
        }
        esp[idx] = (mask != 0.f) ? acc : 0.f;
    }
}

// ============ one-time weight conversion to bf16 (+ rank-2 columns) ============
__global__ __launch_bounds__(256)
void wcvt_kernel(const float* __restrict__ W1, const float* __restrict__ W2,
                 const float* __restrict__ W3,
                 short* __restrict__ W1b, short* __restrict__ W2b,
                 short* __restrict__ W3b, float* __restrict__ w1q,
                 float* __restrict__ w1e)
{
    int i = blockIdx.x * 256 + threadIdx.x;
    if (i < 160 * 384) {
        int r = i / 384, cc = i % 384;
        W1b[i] = f2b(W1[(size_t)r * 386 + cc]);
    }
    int j = i - 160 * 384;
    if (j >= 0 && j < 128 * 160) W2b[j] = f2b(W2[j]);
    int k2 = j - 128 * 160;
    if (k2 >= 0 && k2 < 96 * 128) W3b[k2] = f2b(W3[k2]);
    if (i < 160) {
        w1q[i] = W1[(size_t)i * 386 + 384];
        w1e[i] = W1[(size_t)i * 386 + 385];
    }
}

// ---------------- output: [species as float | charges] ----------------
__global__ __launch_bounds__(256)
void out_kernel(const int* __restrict__ species, const float* __restrict__ q,
                float* __restrict__ out)
{
    int i = blockIdx.x * 256 + threadIdx.x;
    out[i] = (float)species[i];
    out[NN + i] = q[i];
}

extern "C" void kernel_launch(void* const* d_in, const int* in_sizes, int n_in,
                              void* d_out, int out_size, void* d_ws, size_t ws_size,
                              hipStream_t stream)
{
    const int*   species = (const int*)  d_in[0];
    const float* coords  = (const float*)d_in[1];
    const float* netq    = (const float*)d_in[2];
    const float* aev     = (const float*)d_in[3];
    const float* W1 = (const float*)d_in[4];
    const float* b1 = (const float*)d_in[5];
    const float* W2 = (const float*)d_in[6];
    const float* b2 = (const float*)d_in[7];
    const float* W3 = (const float*)d_in[8];
    const float* b3 = (const float*)d_in[9];
    const float* W4 = (const float*)d_in[10];
    const float* b4 = (const float*)d_in[11];

    float* q    = (float*)d_ws;                 // NN
    float* chi  = q + NN;                       // NN
    float* espp = chi + NN;                     // 4*NN partial planes
    float* w1q  = espp + 4 * (size_t)NN;        // 160
    float* w1e  = w1q + 160;                    // 160
    short* W1b  = (short*)(w1e + 160);          // 160*384
    short* W2b  = W1b + 160 * 384;              // 128*160
    short* W3b  = W2b + 128 * 160;              // 96*128
    short* h1p  = W3b + 96 * 128;               // NN*160 bf16
    short* h2   = h1p + (size_t)NN * 160;       // NN*128 bf16
    _Float16* J = (_Float16*)(h2 + (size_t)NN * 128);   // NN*384 fp16

    const size_t NEED = (size_t)((char*)(J + (size_t)NN * 384) - (char*)d_ws);
    const bool use_J = (ws_size >= NEED);

    // zero q + espp planes (iteration-0 features; unused planes stay 0 in fallback)
    hipMemsetAsync(d_ws, 0, 6 * (size_t)NN * sizeof(float), stream);
    wcvt_kernel<<<(160 * 384 + 128 * 160 + 96 * 128 + 255) / 256, 256, 0, stream>>>(
        W1, W2, W3, W1b, W2b, W3b, w1q, w1e);

    if (use_J)
        jbuild_kernel<<<dim3(NMOL, 8), 384, 0, stream>>>(coords, species, J);

    // iteration-invariant: h1p = aev @ W1[:, :384]^T + b1
    gemm_k<160, 384, 0><<<NN / 64, 256, 0, stream>>>(
        aev, W1b, b1, nullptr, nullptr, nullptr, nullptr, nullptr, nullptr, nullptr,
        h1p, nullptr);

    for (int it = 0; it < 4; ++it) {
        gemm_k<128, 160, 1><<<NN / 64, 256, 0, stream>>>(
            h1p, W2b, b2, q, espp, w1q, w1e, nullptr, nullptr, nullptr, h2, nullptr);
        gemm_k<96, 128, 2><<<NN / 64, 256, 0, stream>>>(
            h2, W3b, b3, nullptr, nullptr, nullptr, nullptr, W4, b4, species,
            nullptr, chi);
        if (use_J) {
            if (it < 3)
                espmv_kernel<true><<<dim3(NMOL, 4), 384, 0, stream>>>(
                    chi, species, netq, J, q, espp);
            else
                espmv_kernel<false><<<dim3(NMOL, 1), 384, 0, stream>>>(
                    chi, species, netq, J, q, espp);
        } else {
            if (it < 3)
                espq_kernel<true><<<NMOL, 384, 0, stream>>>(
                    chi, species, netq, coords, q, espp);
            else
                espq_kernel<false><<<NMOL, 384, 0, stream>>>(
                    chi, species, netq, coords, q, espp);
        }
    }

    out_kernel<<<NN / 256, 256, 0, stream>>>(species, q, (float*)d_out);
}

// Round 6
// 304.632 us; speedup vs baseline: 6.0933x; 1.0774x over previous
//
#include <hip/hip_runtime.h>
#include <math.h>

#define NMOL 256
#define NATOM 384
#define NN (NMOL*NATOM)          // 98304
#define A0C  0.529177249f
#define A0_INV (1.0f/0.529177249f)

typedef short bf16x8 __attribute__((ext_vector_type(8)));
typedef float f32x4  __attribute__((ext_vector_type(4)));
typedef _Float16 h16x8 __attribute__((ext_vector_type(8)));

__constant__ float c_sigma[8] = {0.5515909f, 1.8886297f, 1.3225029f, 1.2316629f,
                                 2.1884933f, 1.7750372f, 1.3677907f, 1.3820058f};

__device__ __forceinline__ short f2b(float f) {           // f32 -> bf16 RNE
    unsigned u = __float_as_uint(f);
    u = (u + 0x7fffu + ((u >> 16) & 1u)) >> 16;
    return (short)u;
}
__device__ __forceinline__ float b2f(short s) {
    return __uint_as_float(((unsigned)(unsigned short)s) << 16);
}
__device__ __forceinline__ float celu01(float v) {
    return v > 0.f ? v : 0.1f * expm1f(10.f * v);
}
__device__ __forceinline__ bf16x8 cvt8(f32x4 a, f32x4 b) {
    bf16x8 r;
    r[0] = f2b(a.x); r[1] = f2b(a.y); r[2] = f2b(a.z); r[3] = f2b(a.w);
    r[4] = f2b(b.x); r[5] = f2b(b.y); r[6] = f2b(b.z); r[7] = f2b(b.w);
    return r;
}

// fast erf (x>=0): Abramowitz-Stegun 7.1.26, |abs err| <= 1.5e-7
__device__ __forceinline__ float erf_fast(float x) {
    float t = __builtin_amdgcn_rcpf(fmaf(0.3275911f, x, 1.0f));
    float p = fmaf(t, 1.061405429f, -1.453152027f);
    p = fmaf(t, p, 1.421413741f);
    p = fmaf(t, p, -0.284496736f);
    p = fmaf(t, p, 0.254829592f);
    p = p * t;
    float e = __builtin_amdgcn_exp2f(-x * x * 1.4426950408889634f);
    return fmaf(-p, e, 1.0f);
}

// ======================= MODE0 MFMA GEMM: h1p = aev @ W1a^T + b1 =======================
// BM=64 rows/block, 256 thr = 4 waves (2 row-halves x 2 col-halves)
template<int N, int K>
__global__ __launch_bounds__(256, 4)
void gemm0_k(const float* __restrict__ A, const short* __restrict__ Bw,
             const float* __restrict__ bias, short* __restrict__ Cout)
{
    constexpr int NK = K / 32;
    constexpr int NF = N / 32;
    constexpr int N2 = N / 2;
    constexpr int AROW = 40, BROW = 40;
    constexpr int ASZ = 64 * AROW;
    constexpr int BSZ = N * BROW;
    constexpr int AB  = 2 * ASZ + 2 * BSZ;
    constexpr int CSZ = 64 * N;
    constexpr int SM  = AB > CSZ ? AB : CSZ;
    constexpr int NB  = (N * 4 + 255) / 256;

    __shared__ short smem[SM];
    short* As0 = smem;
    short* As1 = smem + ASZ;
    short* Bs0 = smem + 2 * ASZ;
    short* Bs1 = smem + 2 * ASZ + BSZ;
    short* Cs  = smem;

    const int t    = threadIdx.x;
    const int lane = t & 63;
    const int wave = t >> 6;
    const int wm   = wave >> 1, wn = wave & 1;
    const int l15  = lane & 15, l4 = lane >> 4;
    const int m0   = blockIdx.x * 64;
    const int arow = t >> 2, aseg = t & 3;
    const float* a_f32 = A + ((size_t)m0 + arow) * K + aseg * 8;

    f32x4 af0, af1;
    bf16x8 br[NB];

    auto loadA = [&](int k0) {
        af0 = *(const f32x4*)(a_f32 + k0);
        af1 = *(const f32x4*)(a_f32 + k0 + 4);
    };
    auto loadB = [&](int k0) {
        #pragma unroll
        for (int ci = 0; ci < NB; ++ci) {
            int c = ci * 256 + t;
            if ((N * 4) % 256 == 0 || c < N * 4) {
                int row = c >> 2, half = c & 3;
                br[ci] = *(const bf16x8*)(Bw + (size_t)row * K + k0 + half * 8);
            }
        }
    };
    auto writeA = [&](short* dst) {
        *(bf16x8*)&dst[arow * AROW + aseg * 8] = cvt8(af0, af1);
    };
    auto writeB = [&](short* dst) {
        #pragma unroll
        for (int ci = 0; ci < NB; ++ci) {
            int c = ci * 256 + t;
            if ((N * 4) % 256 == 0 || c < N * 4) {
                int row = c >> 2, half = c & 3;
                *(bf16x8*)&dst[row * BROW + half * 8] = br[ci];
            }
        }
    };

    f32x4 acc[2][NF] = {};

    loadA(0); loadB(0);
    writeA(As0); writeB(Bs0);
    __syncthreads();

    int cur = 0;
    for (int ks = 0; ks < NK; ++ks) {
        if (ks + 1 < NK) { loadA((ks + 1) * 32); loadB((ks + 1) * 32); }
        short* Ac = cur ? As1 : As0;
        short* Bc = cur ? Bs1 : Bs0;
        bf16x8 a[2];
        #pragma unroll
        for (int mf = 0; mf < 2; ++mf)
            a[mf] = *(const bf16x8*)&Ac[(wm * 32 + mf * 16 + l15) * AROW + l4 * 8];
        #pragma unroll
        for (int nf = 0; nf < NF; ++nf) {
            bf16x8 b = *(const bf16x8*)&Bc[(wn * N2 + nf * 16 + l15) * BROW + l4 * 8];
            #pragma unroll
            for (int mf = 0; mf < 2; ++mf)
                acc[mf][nf] = __builtin_amdgcn_mfma_f32_16x16x32_bf16(a[mf], b, acc[mf][nf], 0, 0, 0);
        }
        if (ks + 1 < NK) {
            writeA(cur ? As0 : As1);
            writeB(cur ? Bs0 : Bs1);
            __syncthreads();
            cur ^= 1;
        }
    }
    __syncthreads();

    #pragma unroll
    for (int nf = 0; nf < NF; ++nf) {
        int col = wn * N2 + nf * 16 + l15;
        float bc = bias[col];
        #pragma unroll
        for (int mf = 0; mf < 2; ++mf)
            #pragma unroll
            for (int r = 0; r < 4; ++r)
                Cs[(wm * 32 + mf * 16 + l4 * 4 + r) * N + col] = f2b(acc[mf][nf][r] + bc);
    }
    __syncthreads();
    #pragma unroll
    for (int i = 0; i < NF; ++i) {
        int c = i * 256 + t;
        *(bf16x8*)(Cout + (size_t)m0 * N + c * 8) = *(const bf16x8*)&Cs[c * 8];
    }
}

// ======================= fused layers 2+3+4 =======================
// h2(LDS) = celu( celu(h1p + q*w1q + esp*w1e) @ W2^T + b2 )   [K=160 -> N=128]
// h3      = celu( h2 @ W3^T + b3 )                            [K=128 -> N=96, in-reg]
// chi     = mask * softplus( h3 . W4 + b4 )
__global__ __launch_bounds__(256, 3)
void mlp23_kernel(const short* __restrict__ h1p, const short* __restrict__ W2b,
                  const float* __restrict__ b2, const short* __restrict__ W3b,
                  const float* __restrict__ b3, const float* __restrict__ W4,
                  const float* __restrict__ b4,
                  const float* __restrict__ qv, const float* __restrict__ espv,
                  const float* __restrict__ w1qp, const float* __restrict__ w1ep,
                  const int* __restrict__ species, float* __restrict__ chi)
{
    constexpr int K1 = 160, N1 = 128, K2 = 128, N3 = 96;
    constexpr int AROW = 40, BROW = 40, H2ROW = 136;

    __shared__ short As[2][64 * AROW];
    __shared__ short Bs[2][N1 * BROW];
    __shared__ short H2[64 * H2ROW];
    __shared__ float wq_s[K1], we_s[K1], w4_s[N3], b3_s[N3];
    __shared__ float chp[2][64];

    const int t    = threadIdx.x;
    const int lane = t & 63;
    const int wave = t >> 6;
    const int wm   = wave >> 1, wn = wave & 1;
    const int l15  = lane & 15, l4 = lane >> 4;
    const int m0   = blockIdx.x * 64;
    const int arow = t >> 2, aseg = t & 3;
    const size_t agrow = (size_t)m0 + arow;

    if (t < K1) { wq_s[t] = w1qp[t]; we_s[t] = w1ep[t]; }
    if (t < N3) { w4_s[t] = W4[t]; b3_s[t] = b3[t]; }

    const short* a_b16 = h1p + agrow * K1 + aseg * 8;
    const float qr = qv[agrow];
    const float er = espv[agrow] + espv[NN + agrow] + espv[2 * (size_t)NN + agrow]
                   + espv[3 * (size_t)NN + agrow];

    bf16x8 ah;
    bf16x8 br[2];

    auto loadA = [&](int k0) { ah = *(const bf16x8*)(a_b16 + k0); };
    auto loadB1 = [&](int k0) {
        #pragma unroll
        for (int ci = 0; ci < 2; ++ci) {
            int c = ci * 256 + t;
            int row = c >> 2, half = c & 3;
            br[ci] = *(const bf16x8*)(W2b + (size_t)row * K1 + k0 + half * 8);
        }
    };
    auto writeA = [&](short* dst, int k0) {
        bf16x8 o;
        #pragma unroll
        for (int j = 0; j < 8; ++j) {
            float v = b2f(ah[j]) + qr * wq_s[k0 + aseg * 8 + j]
                                 + er * we_s[k0 + aseg * 8 + j];
            o[j] = f2b(celu01(v));
        }
        *(bf16x8*)&dst[arow * AROW + aseg * 8] = o;
    };
    auto writeB1 = [&](short* dst) {
        #pragma unroll
        for (int ci = 0; ci < 2; ++ci) {
            int c = ci * 256 + t;
            int row = c >> 2, half = c & 3;
            *(bf16x8*)&dst[row * BROW + half * 8] = br[ci];
        }
    };

    // ---------------- stage 1: K=160 -> h2 tile (LDS) ----------------
    f32x4 acc[2][4] = {};
    loadA(0); loadB1(0);
    __syncthreads();                 // wq_s/we_s ready
    writeA(As[0], 0); writeB1(Bs[0]);
    __syncthreads();

    int cur = 0;
    for (int ks = 0; ks < 5; ++ks) {
        if (ks + 1 < 5) { loadA((ks + 1) * 32); loadB1((ks + 1) * 32); }
        const short* Ac = As[cur];
        const short* Bc = Bs[cur];
        bf16x8 a[2];
        #pragma unroll
        for (int mf = 0; mf < 2; ++mf)
            a[mf] = *(const bf16x8*)&Ac[(wm * 32 + mf * 16 + l15) * AROW + l4 * 8];
        #pragma unroll
        for (int nf = 0; nf < 4; ++nf) {
            bf16x8 b = *(const bf16x8*)&Bc[(wn * 64 + nf * 16 + l15) * BROW + l4 * 8];
            #pragma unroll
            for (int mf = 0; mf < 2; ++mf)
                acc[mf][nf] = __builtin_amdgcn_mfma_f32_16x16x32_bf16(a[mf], b, acc[mf][nf], 0, 0, 0);
        }
        if (ks + 1 < 5) {
            writeA(As[cur ^ 1], (ks + 1) * 32);
            writeB1(Bs[cur ^ 1]);
            __syncthreads();
            cur ^= 1;
        }
    }

    // h2 tile -> LDS (padded), celu applied
    #pragma unroll
    for (int nf = 0; nf < 4; ++nf) {
        int col = wn * 64 + nf * 16 + l15;
        float bc = b2[col];
        #pragma unroll
        for (int mf = 0; mf < 2; ++mf)
            #pragma unroll
            for (int r = 0; r < 4; ++r)
                H2[(wm * 32 + mf * 16 + l4 * 4 + r) * H2ROW + col] =
                    f2b(celu01(acc[mf][nf][r] + bc));
    }

    // ---------------- stage 2: K=128, N=96, A from LDS H2 ----------------
    auto loadB2 = [&](int k0) {
        #pragma unroll
        for (int ci = 0; ci < 2; ++ci) {
            int c = ci * 256 + t;
            if (c < N3 * 4) {
                int row = c >> 2, half = c & 3;
                br[ci] = *(const bf16x8*)(W3b + (size_t)row * K2 + k0 + half * 8);
            }
        }
    };
    auto writeB2 = [&](short* dst) {
        #pragma unroll
        for (int ci = 0; ci < 2; ++ci) {
            int c = ci * 256 + t;
            if (c < N3 * 4) {
                int row = c >> 2, half = c & 3;
                *(bf16x8*)&dst[row * BROW + half * 8] = br[ci];
            }
        }
    };

    loadB2(0);
    __syncthreads();                 // H2 complete; stage-1 Bs reads done
    writeB2(Bs[0]);
    __syncthreads();

    f32x4 acc2[2][3] = {};
    cur = 0;
    for (int ks = 0; ks < 4; ++ks) {
        if (ks + 1 < 4) loadB2((ks + 1) * 32);
        const short* Bc = Bs[cur];
        bf16x8 a[2];
        #pragma unroll
        for (int mf = 0; mf < 2; ++mf)
            a[mf] = *(const bf16x8*)&H2[(wm * 32 + mf * 16 + l15) * H2ROW + ks * 32 + l4 * 8];
        #pragma unroll
        for (int nf = 0; nf < 3; ++nf) {
            bf16x8 b = *(const bf16x8*)&Bc[(wn * 48 + nf * 16 + l15) * BROW + l4 * 8];
            #pragma unroll
            for (int mf = 0; mf < 2; ++mf)
                acc2[mf][nf] = __builtin_amdgcn_mfma_f32_16x16x32_bf16(a[mf], b, acc2[mf][nf], 0, 0, 0);
        }
        if (ks + 1 < 4) {
            writeB2(Bs[cur ^ 1]);
            __syncthreads();
            cur ^= 1;
        }
    }

    // ---------------- chi epilogue: celu -> .W4 -> lane reduce -> softplus ----------------
    float val[2][4];
    #pragma unroll
    for (int mf = 0; mf < 2; ++mf)
        #pragma unroll
        for (int r = 0; r < 4; ++r) val[mf][r] = 0.f;
    #pragma unroll
    for (int nf = 0; nf < 3; ++nf) {
        int col = wn * 48 + nf * 16 + l15;
        float bc = b3_s[col];
        float wc = w4_s[col];
        #pragma unroll
        for (int mf = 0; mf < 2; ++mf)
            #pragma unroll
            for (int r = 0; r < 4; ++r)
                val[mf][r] += celu01(acc2[mf][nf][r] + bc) * wc;
    }
    #pragma unroll
    for (int off = 1; off < 16; off <<= 1)
        #pragma unroll
        for (int mf = 0; mf < 2; ++mf)
            #pragma unroll
            for (int r = 0; r < 4; ++r)
                val[mf][r] += __shfl_xor(val[mf][r], off, 64);
    if (l15 == 0) {
        #pragma unroll
        for (int mf = 0; mf < 2; ++mf)
            #pragma unroll
            for (int r = 0; r < 4; ++r)
                chp[wn][wm * 32 + mf * 16 + l4 * 4 + r] = val[mf][r];
    }
    __syncthreads();
    if (t < 64) {
        float s = chp[0][t] + chp[1][t] + b4[0];
        s = fmaxf(s, 0.f) + log1pf(expf(-fabsf(s)));   // softplus
        chi[m0 + t] = (species[m0 + t] != -1) ? s : 0.f;
    }
}

// ============ J-matrix build (iteration-invariant), fp16, masked ============
__global__ __launch_bounds__(384)
void jbuild_kernel(const float* __restrict__ coords, const int* __restrict__ species,
                   _Float16* __restrict__ J)
{
    __shared__ float cx[NATOM], cy[NATOM], cz[NATOM], s2[NATOM], mk[NATOM];
    int m = blockIdx.x, it0 = blockIdx.y * 48;
    int j = threadIdx.x;
    int idx = m * NATOM + j;
    float rx = coords[(size_t)idx * 3 + 0];
    float ry = coords[(size_t)idx * 3 + 1];
    float rz = coords[(size_t)idx * 3 + 2];
    int sp = species[idx];
    float sig = c_sigma[sp < 0 ? 7 : sp];
    cx[j] = rx; cy[j] = ry; cz[j] = rz;
    s2[j] = sig * sig;
    float maskj = (sp != -1) ? 1.f : 0.f;
    mk[j] = maskj;
    __syncthreads();
    float s2j = s2[j];
    #pragma unroll 4
    for (int ii = 0; ii < 48; ++ii) {
        int i = it0 + ii;
        float dx = cx[i] - rx, dy = cy[i] - ry, dz = cz[i] - rz;
        float d2 = fmaf(dx, dx, fmaf(dy, dy, dz * dz)) + 1e-16f;
        float rs = __builtin_amdgcn_rsqf(d2);           // 1/sqrt(d2)
        float d  = d2 * rs * A0_INV;                    // |r|/A0 (Bohr)
        float ss = fmaxf(s2[i] + s2j, 1e-8f);
        float x  = d * __builtin_amdgcn_rsqf(2.f * ss);
        float val = erf_fast(x) * rs * A0C;             // erf(x)/d
        val *= maskj * mk[i];
        val = (i == j) ? 0.f : val;
        J[((size_t)m * NATOM + i) * NATOM + j] = (_Float16)val;
    }
}

// ============ fused charge normalization + ESP matvec partials ============
template<bool DO_MV>
__global__ __launch_bounds__(384)
void espmv_kernel(const float* __restrict__ chi, const int* __restrict__ species,
                  const float* __restrict__ netq, const _Float16* __restrict__ J,
                  float* __restrict__ q, float* __restrict__ esp_part)
{
    __shared__ float red[512], redc[512];
    __shared__ float qs[DO_MV ? 96 : 1];
    __shared__ float part[DO_MV ? 8 : 1][DO_MV ? 384 : 1];
    int m = blockIdx.x, ic = blockIdx.y;
    int t = threadIdx.x;
    int idx = m * NATOM + t;
    float c = chi[idx];
    int sp = species[idx];
    float mask = (sp != -1) ? 1.f : 0.f;
    red[t] = c; redc[t] = mask;
    if (t < 128) { red[NATOM + t] = 0.f; redc[NATOM + t] = 0.f; }
    __syncthreads();
    for (int s = 256; s > 0; s >>= 1) {
        if (t < s) { red[t] += red[t + s]; redc[t] += redc[t + s]; }
        __syncthreads();
    }
    float chi_sum = red[0], na = redc[0];
    float Q = netq[m];
    float k_net = 1.f + fabsf(Q) / chi_sum;
    float chi_mean = chi_sum / na;
    float k_p = (Q > 0.f) ? k_net : 1.f;
    float k_n = (Q < 0.f) ? k_net : 1.f;
    float qj = (-k_n * c + k_p * chi_mean) * mask;
    if (ic == 0) q[idx] = qj;

    if (DO_MV) {
        if (t >= ic * 96 && t < ic * 96 + 96) qs[t - ic * 96] = qj;
        __syncthreads();
        int jv = t % 48, isub = t / 48;
        int j0 = jv * 8;
        float acc[8] = {};
        #pragma unroll 4
        for (int k = 0; k < 12; ++k) {
            int il = isub * 12 + k;
            int i = ic * 96 + il;
            h16x8 h = *(const h16x8*)&J[((size_t)m * NATOM + i) * NATOM + j0];
            float qi = qs[il];
            #pragma unroll
            for (int r = 0; r < 8; ++r) acc[r] = fmaf(qi, (float)h[r], acc[r]);
        }
        #pragma unroll
        for (int r = 0; r < 8; ++r) part[isub][j0 + r] = acc[r];
        __syncthreads();
        float s = 0.f;
        #pragma unroll
        for (int g = 0; g < 8; ++g) s += part[g][t];
        esp_part[(size_t)ic * NN + idx] = s;
    }
}

// ============ fallback: direct charge+ESP (ws too small for J) ============
template<bool DO_ESP>
__global__ __launch_bounds__(384)
void espq_kernel(const float* __restrict__ chi, const int* __restrict__ species,
                 const float* __restrict__ netq, const float* __restrict__ coords,
                 float* __restrict__ q, float* __restrict__ esp)
{
    __shared__ float red[512], redc[512];
    __shared__ float cx[NATOM], cy[NATOM], cz[NATOM], s2[NATOM], qs[NATOM];
    int m = blockIdx.x, j = threadIdx.x;
    int idx = m * NATOM + j;
    float c = chi[idx];
    int sp = species[idx];
    float mask = (sp != -1) ? 1.f : 0.f;
    red[j] = c; redc[j] = mask;
    if (j < 128) { red[NATOM + j] = 0.f; redc[NATOM + j] = 0.f; }
    __syncthreads();
    for (int s = 256; s > 0; s >>= 1) {
        if (j < s) { red[j] += red[j + s]; redc[j] += redc[j + s]; }
        __syncthreads();
    }
    float chi_sum = red[0], na = redc[0];
    float Q = netq[m];
    float k_net = 1.f + fabsf(Q) / chi_sum;
    float chi_mean = chi_sum / na;
    float k_p = (Q > 0.f) ? k_net : 1.f;
    float k_n = (Q < 0.f) ? k_net : 1.f;
    float qj = (-k_n * c + k_p * chi_mean) * mask;
    q[idx] = qj;

    if (DO_ESP) {
        float rx = coords[(size_t)idx * 3 + 0];
        float ry = coords[(size_t)idx * 3 + 1];
        float rz = coords[(size_t)idx * 3 + 2];
        cx[j] = rx; cy[j] = ry; cz[j] = rz;
        float sig = c_sigma[sp < 0 ? 7 : sp];
        s2[j] = sig * sig;
        qs[j] = qj;
        __syncthreads();
        float s2j = s2[j];
        float acc = 0.f;
        for (int i = 0; i < NATOM; ++i) {
            float dx = cx[i] - rx, dy = cy[i] - ry, dz = cz[i] - rz;
            float d2 = fmaf(dx, dx, fmaf(dy, dy, dz * dz)) + 1e-16f;
            float rs = __builtin_amdgcn_rsqf(d2);
            float d  = d2 * rs * A0_INV;
            float ss = fmaxf(s2[i] + s2j, 1e-8f);
            float x  = d * __builtin_amdgcn_rsqf(2.f * ss);
            float val = erf_fast(x) * rs * A0C;
            acc += (i == j) ? 0.f : qs[i] * val;
        }
        esp[idx] = (mask != 0.f) ? acc : 0.f;
    }
}

// ============ one-time weight conversion to bf16 (+ rank-2 columns) ============
__global__ __launch_bounds__(256)
void wcvt_kernel(const float* __restrict__ W1, const float* __restrict__ W2,
                 const float* __restrict__ W3,
                 short* __restrict__ W1b, short* __restrict__ W2b,
                 short* __restrict__ W3b, float* __restrict__ w1q,
                 float* __restrict__ w1e)
{
    int i = blockIdx.x * 256 + threadIdx.x;
    if (i < 160 * 384) {
        int r = i / 384, cc = i % 384;
        W1b[i] = f2b(W1[(size_t)r * 386 + cc]);
    }
    int j = i - 160 * 384;
    if (j >= 0 && j < 128 * 160) W2b[j] = f2b(W2[j]);
    int k2 = j - 128 * 160;
    if (k2 >= 0 && k2 < 96 * 128) W3b[k2] = f2b(W3[k2]);
    if (i < 160) {
        w1q[i] = W1[(size_t)i * 386 + 384];
        w1e[i] = W1[(size_t)i * 386 + 385];
    }
}

// ---------------- output: [species as float | charges] ----------------
__global__ __launch_bounds__(256)
void out_kernel(const int* __restrict__ species, const float* __restrict__ q,
                float* __restrict__ out)
{
    int i = blockIdx.x * 256 + threadIdx.x;
    out[i] = (float)species[i];
    out[NN + i] = q[i];
}

extern "C" void kernel_launch(void* const* d_in, const int* in_sizes, int n_in,
                              void* d_out, int out_size, void* d_ws, size_t ws_size,
                              hipStream_t stream)
{
    const int*   species = (const int*)  d_in[0];
    const float* coords  = (const float*)d_in[1];
    const float* netq    = (const float*)d_in[2];
    const float* aev     = (const float*)d_in[3];
    const float* W1 = (const float*)d_in[4];
    const float* b1 = (const float*)d_in[5];
    const float* W2 = (const float*)d_in[6];
    const float* b2 = (const float*)d_in[7];
    const float* W3 = (const float*)d_in[8];
    const float* b3 = (const float*)d_in[9];
    const float* W4 = (const float*)d_in[10];
    const float* b4 = (const float*)d_in[11];

    float* q    = (float*)d_ws;                 // NN
    float* chi  = q + NN;                       // NN
    float* espp = chi + NN;                     // 4*NN partial planes
    float* w1q  = espp + 4 * (size_t)NN;        // 160
    float* w1e  = w1q + 160;                    // 160
    short* W1b  = (short*)(w1e + 160);          // 160*384
    short* W2b  = W1b + 160 * 384;              // 128*160
    short* W3b  = W2b + 128 * 160;              // 96*128
    short* h1p  = W3b + 96 * 128;               // NN*160 bf16
    _Float16* J = (_Float16*)(h1p + (size_t)NN * 160);  // NN*384 fp16

    const size_t NEED = (size_t)((char*)(J + (size_t)NN * 384) - (char*)d_ws);
    const bool use_J = (ws_size >= NEED);

    // zero q + espp planes (iteration-0 features; unused planes stay 0 in fallback)
    hipMemsetAsync(d_ws, 0, 6 * (size_t)NN * sizeof(float), stream);
    wcvt_kernel<<<(160 * 384 + 128 * 160 + 96 * 128 + 255) / 256, 256, 0, stream>>>(
        W1, W2, W3, W1b, W2b, W3b, w1q, w1e);

    if (use_J)
        jbuild_kernel<<<dim3(NMOL, 8), 384, 0, stream>>>(coords, species, J);

    // iteration-invariant: h1p = aev @ W1[:, :384]^T + b1
    gemm0_k<160, 384><<<NN / 64, 256, 0, stream>>>(aev, W1b, b1, h1p);

    for (int it = 0; it < 4; ++it) {
        mlp23_kernel<<<NN / 64, 256, 0, stream>>>(
            h1p, W2b, b2, W3b, b3, W4, b4, q, espp, w1q, w1e, species, chi);
        if (use_J) {
            if (it < 3)
                espmv_kernel<true><<<dim3(NMOL, 4), 384, 0, stream>>>(
                    chi, species, netq, J, q, espp);
            else
                espmv_kernel<false><<<dim3(NMOL, 1), 384, 0, stream>>>(
                    chi, species, netq, J, q, espp);
        } else {
            if (it < 3)
                espq_kernel<true><<<NMOL, 384, 0, stream>>>(
                    chi, species, netq, coords, q, espp);
            else
                espq_kernel<false><<<NMOL, 384, 0, stream>>>(
                    chi, species, netq, coords, q, espp);
        }
    }

    out_kernel<<<NN / 256, 256, 0, stream>>>(species, q, (float*)d_out);
}

// Round 7
// 257.368 us; speedup vs baseline: 7.2122x; 1.1836x over previous
//
#include <hip/hip_runtime.h>
#include <math.h>

#define NMOL 256
#define NATOM 384
#define NN (NMOL*NATOM)          // 98304
#define A0C  0.529177249f
#define A0_INV (1.0f/0.529177249f)

typedef short bf16x8 __attribute__((ext_vector_type(8)));
typedef float f32x4  __attribute__((ext_vector_type(4)));
typedef _Float16 h16x8 __attribute__((ext_vector_type(8)));

__constant__ float c_sigma[8] = {0.5515909f, 1.8886297f, 1.3225029f, 1.2316629f,
                                 2.1884933f, 1.7750372f, 1.3677907f, 1.3820058f};

__device__ __forceinline__ short f2b(float f) {           // f32 -> bf16 RNE
    unsigned u = __float_as_uint(f);
    u = (u + 0x7fffu + ((u >> 16) & 1u)) >> 16;
    return (short)u;
}
__device__ __forceinline__ float b2f(short s) {
    return __uint_as_float(((unsigned)(unsigned short)s) << 16);
}
// cheap celu(alpha=0.1): 0.1*(e^(10v)-1) = 0.1*exp2(10v*log2e)-0.1
__device__ __forceinline__ float celu01(float v) {
    float e = __builtin_amdgcn_exp2f(v * 14.426950408889634f);
    return v > 0.f ? v : fmaf(0.1f, e, -0.1f);
}
__device__ __forceinline__ bf16x8 cvt8(f32x4 a, f32x4 b) {
    bf16x8 r;
    r[0] = f2b(a.x); r[1] = f2b(a.y); r[2] = f2b(a.z); r[3] = f2b(a.w);
    r[4] = f2b(b.x); r[5] = f2b(b.y); r[6] = f2b(b.z); r[7] = f2b(b.w);
    return r;
}

// fast erf (x>=0): Abramowitz-Stegun 7.1.26, |abs err| <= 1.5e-7
__device__ __forceinline__ float erf_fast(float x) {
    float t = __builtin_amdgcn_rcpf(fmaf(0.3275911f, x, 1.0f));
    float p = fmaf(t, 1.061405429f, -1.453152027f);
    p = fmaf(t, p, 1.421413741f);
    p = fmaf(t, p, -0.284496736f);
    p = fmaf(t, p, 0.254829592f);
    p = p * t;
    float e = __builtin_amdgcn_exp2f(-x * x * 1.4426950408889634f);
    return fmaf(-p, e, 1.0f);
}

// ======================= MODE0 MFMA GEMM: h1p = aev @ W1a^T + b1 =======================
// BM=64 rows/block, 256 thr = 4 waves (2 row-halves x 2 col-halves)
template<int N, int K>
__global__ __launch_bounds__(256, 4)
void gemm0_k(const float* __restrict__ A, const short* __restrict__ Bw,
             const float* __restrict__ bias, short* __restrict__ Cout)
{
    constexpr int NK = K / 32;
    constexpr int NF = N / 32;
    constexpr int N2 = N / 2;
    constexpr int AROW = 40, BROW = 40;
    constexpr int ASZ = 64 * AROW;
    constexpr int BSZ = N * BROW;
    constexpr int AB  = 2 * ASZ + 2 * BSZ;
    constexpr int CSZ = 64 * N;
    constexpr int SM  = AB > CSZ ? AB : CSZ;
    constexpr int NB  = (N * 4 + 255) / 256;

    __shared__ short smem[SM];
    short* As0 = smem;
    short* As1 = smem + ASZ;
    short* Bs0 = smem + 2 * ASZ;
    short* Bs1 = smem + 2 * ASZ + BSZ;
    short* Cs  = smem;

    const int t    = threadIdx.x;
    const int lane = t & 63;
    const int wave = t >> 6;
    const int wm   = wave >> 1, wn = wave & 1;
    const int l15  = lane & 15, l4 = lane >> 4;
    const int m0   = blockIdx.x * 64;
    const int arow = t >> 2, aseg = t & 3;
    const float* a_f32 = A + ((size_t)m0 + arow) * K + aseg * 8;

    f32x4 af0, af1;
    bf16x8 br[NB];

    auto loadA = [&](int k0) {
        af0 = *(const f32x4*)(a_f32 + k0);
        af1 = *(const f32x4*)(a_f32 + k0 + 4);
    };
    auto loadB = [&](int k0) {
        #pragma unroll
        for (int ci = 0; ci < NB; ++ci) {
            int c = ci * 256 + t;
            if ((N * 4) % 256 == 0 || c < N * 4) {
                int row = c >> 2, half = c & 3;
                br[ci] = *(const bf16x8*)(Bw + (size_t)row * K + k0 + half * 8);
            }
        }
    };
    auto writeA = [&](short* dst) {
        *(bf16x8*)&dst[arow * AROW + aseg * 8] = cvt8(af0, af1);
    };
    auto writeB = [&](short* dst) {
        #pragma unroll
        for (int ci = 0; ci < NB; ++ci) {
            int c = ci * 256 + t;
            if ((N * 4) % 256 == 0 || c < N * 4) {
                int row = c >> 2, half = c & 3;
                *(bf16x8*)&dst[row * BROW + half * 8] = br[ci];
            }
        }
    };

    f32x4 acc[2][NF] = {};

    loadA(0); loadB(0);
    writeA(As0); writeB(Bs0);
    __syncthreads();

    int cur = 0;
    for (int ks = 0; ks < NK; ++ks) {
        if (ks + 1 < NK) { loadA((ks + 1) * 32); loadB((ks + 1) * 32); }
        short* Ac = cur ? As1 : As0;
        short* Bc = cur ? Bs1 : Bs0;
        bf16x8 a[2];
        #pragma unroll
        for (int mf = 0; mf < 2; ++mf)
            a[mf] = *(const bf16x8*)&Ac[(wm * 32 + mf * 16 + l15) * AROW + l4 * 8];
        #pragma unroll
        for (int nf = 0; nf < NF; ++nf) {
            bf16x8 b = *(const bf16x8*)&Bc[(wn * N2 + nf * 16 + l15) * BROW + l4 * 8];
            #pragma unroll
            for (int mf = 0; mf < 2; ++mf)
                acc[mf][nf] = __builtin_amdgcn_mfma_f32_16x16x32_bf16(a[mf], b, acc[mf][nf], 0, 0, 0);
        }
        if (ks + 1 < NK) {
            writeA(cur ? As0 : As1);
            writeB(cur ? Bs0 : Bs1);
            __syncthreads();
            cur ^= 1;
        }
    }
    __syncthreads();

    #pragma unroll
    for (int nf = 0; nf < NF; ++nf) {
        int col = wn * N2 + nf * 16 + l15;
        float bc = bias[col];
        #pragma unroll
        for (int mf = 0; mf < 2; ++mf)
            #pragma unroll
            for (int r = 0; r < 4; ++r)
                Cs[(wm * 32 + mf * 16 + l4 * 4 + r) * N + col] = f2b(acc[mf][nf][r] + bc);
    }
    __syncthreads();
    #pragma unroll
    for (int i = 0; i < NF; ++i) {
        int c = i * 256 + t;
        *(bf16x8*)(Cout + (size_t)m0 * N + c * 8) = *(const bf16x8*)&Cs[c * 8];
    }
}

// ======================= fused layers 2+3+4, frag-direct =======================
// A and B fragments loaded straight from global (rank-2 + celu applied in regs);
// only the stage-1->2 transpose (H2) lives in LDS. 3 barriers total.
__global__ __launch_bounds__(256, 4)
void mlp23_kernel(const short* __restrict__ h1p, const short* __restrict__ W2b,
                  const float* __restrict__ b2, const short* __restrict__ W3b,
                  const float* __restrict__ b3, const float* __restrict__ W4,
                  const float* __restrict__ b4,
                  const float* __restrict__ qv, const float* __restrict__ espv,
                  const float* __restrict__ w1qp, const float* __restrict__ w1ep,
                  const int* __restrict__ species, float* __restrict__ chi)
{
    constexpr int K1 = 160, K2 = 128, N3 = 96;
    constexpr int H2ROW = 140;     // 280B stride -> ~2-way banks on b128 reads

    __shared__ short H2[64 * H2ROW];
    __shared__ float wq_s[K1], we_s[K1], w4_s[N3], b3_s[N3];
    __shared__ float chp[2][64];

    const int t    = threadIdx.x;
    const int lane = t & 63;
    const int wave = t >> 6;
    const int wm   = wave >> 1, wn = wave & 1;
    const int l15  = lane & 15, l4 = lane >> 4;
    const int m0   = blockIdx.x * 64;

    if (t < K1) { wq_s[t] = w1qp[t]; we_s[t] = w1ep[t]; }
    if (t < N3) { w4_s[t] = W4[t]; b3_s[t] = b3[t]; }

    // per-lane A-row constants (row = l15 within each mf group)
    int rowg[2];
    float qrow[2], erow[2];
    #pragma unroll
    for (int mf = 0; mf < 2; ++mf) {
        rowg[mf] = m0 + wm * 32 + mf * 16 + l15;
        qrow[mf] = qv[rowg[mf]];
        erow[mf] = espv[rowg[mf]] + espv[NN + rowg[mf]]
                 + espv[2 * (size_t)NN + rowg[mf]] + espv[3 * (size_t)NN + rowg[mf]];
    }
    __syncthreads();   // wq_s/we_s visible

    // ---------------- stage 1: celu(h1p + q*w1q + e*w1e) @ W2^T, K=160, no barriers ----------------
    f32x4 acc[2][4] = {};
    #pragma unroll
    for (int ks = 0; ks < 5; ++ks) {
        const int k0 = ks * 32 + l4 * 8;
        f32x4 wq0 = *(const f32x4*)&wq_s[k0];
        f32x4 wq1 = *(const f32x4*)&wq_s[k0 + 4];
        f32x4 we0 = *(const f32x4*)&we_s[k0];
        f32x4 we1 = *(const f32x4*)&we_s[k0 + 4];
        bf16x8 a[2];
        #pragma unroll
        for (int mf = 0; mf < 2; ++mf) {
            bf16x8 h = *(const bf16x8*)(h1p + (size_t)rowg[mf] * K1 + k0);
            #pragma unroll
            for (int j = 0; j < 4; ++j) {
                float v = b2f(h[j]) + qrow[mf] * wq0[j] + erow[mf] * we0[j];
                a[mf][j] = f2b(celu01(v));
                float v2 = b2f(h[j + 4]) + qrow[mf] * wq1[j] + erow[mf] * we1[j];
                a[mf][j + 4] = f2b(celu01(v2));
            }
        }
        #pragma unroll
        for (int nf = 0; nf < 4; ++nf) {
            bf16x8 b = *(const bf16x8*)(W2b + (size_t)(wn * 64 + nf * 16 + l15) * K1 + k0);
            #pragma unroll
            for (int mf = 0; mf < 2; ++mf)
                acc[mf][nf] = __builtin_amdgcn_mfma_f32_16x16x32_bf16(a[mf], b, acc[mf][nf], 0, 0, 0);
        }
    }

    // h2 tile -> LDS (celu applied)
    #pragma unroll
    for (int nf = 0; nf < 4; ++nf) {
        int col = wn * 64 + nf * 16 + l15;
        float bc = b2[col];
        #pragma unroll
        for (int mf = 0; mf < 2; ++mf)
            #pragma unroll
            for (int r = 0; r < 4; ++r)
                H2[(wm * 32 + mf * 16 + l4 * 4 + r) * H2ROW + col] =
                    f2b(celu01(acc[mf][nf][r] + bc));
    }
    __syncthreads();

    // ---------------- stage 2: H2 @ W3^T, K=128, B direct from global ----------------
    f32x4 acc2[2][3] = {};
    #pragma unroll
    for (int ks = 0; ks < 4; ++ks) {
        bf16x8 a[2];
        #pragma unroll
        for (int mf = 0; mf < 2; ++mf)
            a[mf] = *(const bf16x8*)&H2[(wm * 32 + mf * 16 + l15) * H2ROW + ks * 32 + l4 * 8];
        #pragma unroll
        for (int nf = 0; nf < 3; ++nf) {
            bf16x8 b = *(const bf16x8*)(W3b + (size_t)(wn * 48 + nf * 16 + l15) * K2 + ks * 32 + l4 * 8);
            #pragma unroll
            for (int mf = 0; mf < 2; ++mf)
                acc2[mf][nf] = __builtin_amdgcn_mfma_f32_16x16x32_bf16(a[mf], b, acc2[mf][nf], 0, 0, 0);
        }
    }

    // ---------------- chi epilogue: celu -> .W4 -> lane reduce -> softplus ----------------
    float val[2][4];
    #pragma unroll
    for (int mf = 0; mf < 2; ++mf)
        #pragma unroll
        for (int r = 0; r < 4; ++r) val[mf][r] = 0.f;
    #pragma unroll
    for (int nf = 0; nf < 3; ++nf) {
        int col = wn * 48 + nf * 16 + l15;
        float bc = b3_s[col];
        float wc = w4_s[col];
        #pragma unroll
        for (int mf = 0; mf < 2; ++mf)
            #pragma unroll
            for (int r = 0; r < 4; ++r)
                val[mf][r] += celu01(acc2[mf][nf][r] + bc) * wc;
    }
    #pragma unroll
    for (int off = 1; off < 16; off <<= 1)
        #pragma unroll
        for (int mf = 0; mf < 2; ++mf)
            #pragma unroll
            for (int r = 0; r < 4; ++r)
                val[mf][r] += __shfl_xor(val[mf][r], off, 64);
    if (l15 == 0) {
        #pragma unroll
        for (int mf = 0; mf < 2; ++mf)
            #pragma unroll
            for (int r = 0; r < 4; ++r)
                chp[wn][wm * 32 + mf * 16 + l4 * 4 + r] = val[mf][r];
    }
    __syncthreads();
    if (t < 64) {
        float s = chp[0][t] + chp[1][t] + b4[0];
        s = fmaxf(s, 0.f) + log1pf(expf(-fabsf(s)));   // softplus
        chi[m0 + t] = (species[m0 + t] != -1) ? s : 0.f;
    }
}

// ============ J-matrix build (iteration-invariant), fp16, masked ============
__global__ __launch_bounds__(384)
void jbuild_kernel(const float* __restrict__ coords, const int* __restrict__ species,
                   _Float16* __restrict__ J)
{
    __shared__ float cx[NATOM], cy[NATOM], cz[NATOM], s2[NATOM], mk[NATOM];
    int m = blockIdx.x, it0 = blockIdx.y * 48;
    int j = threadIdx.x;
    int idx = m * NATOM + j;
    float rx = coords[(size_t)idx * 3 + 0];
    float ry = coords[(size_t)idx * 3 + 1];
    float rz = coords[(size_t)idx * 3 + 2];
    int sp = species[idx];
    float sig = c_sigma[sp < 0 ? 7 : sp];
    cx[j] = rx; cy[j] = ry; cz[j] = rz;
    s2[j] = sig * sig;
    float maskj = (sp != -1) ? 1.f : 0.f;
    mk[j] = maskj;
    __syncthreads();
    float s2j = s2[j];
    #pragma unroll 4
    for (int ii = 0; ii < 48; ++ii) {
        int i = it0 + ii;
        float dx = cx[i] - rx, dy = cy[i] - ry, dz = cz[i] - rz;
        float d2 = fmaf(dx, dx, fmaf(dy, dy, dz * dz)) + 1e-16f;
        float rs = __builtin_amdgcn_rsqf(d2);           // 1/sqrt(d2)
        float d  = d2 * rs * A0_INV;                    // |r|/A0 (Bohr)
        float ss = fmaxf(s2[i] + s2j, 1e-8f);
        float x  = d * __builtin_amdgcn_rsqf(2.f * ss);
        float val = erf_fast(x) * rs * A0C;             // erf(x)/d
        val *= maskj * mk[i];
        val = (i == j) ? 0.f : val;
        J[((size_t)m * NATOM + i) * NATOM + j] = (_Float16)val;
    }
}

// ============ fused charge normalization + ESP matvec partials ============
// grid (NMOL, DO_MV?4:1), block 384.  Wave-shuffle reduction (2 barriers).
template<bool DO_MV>
__global__ __launch_bounds__(384)
void espmv_kernel(const float* __restrict__ chi, const int* __restrict__ species,
                  const float* __restrict__ netq, const _Float16* __restrict__ J,
                  float* __restrict__ q, float* __restrict__ esp_part)
{
    __shared__ float pw[6], pwc[6];
    __shared__ float qs[DO_MV ? 96 : 1];
    __shared__ float part[DO_MV ? 8 : 1][DO_MV ? 384 : 1];
    int m = blockIdx.x, ic = blockIdx.y;
    int t = threadIdx.x;
    int lane = t & 63, wv = t >> 6;
    int idx = m * NATOM + t;
    float c = chi[idx];
    int sp = species[idx];
    float mask = (sp != -1) ? 1.f : 0.f;
    float sc = c, sm = mask;
    #pragma unroll
    for (int off = 1; off < 64; off <<= 1) {
        sc += __shfl_xor(sc, off, 64);
        sm += __shfl_xor(sm, off, 64);
    }
    if (lane == 0) { pw[wv] = sc; pwc[wv] = sm; }
    __syncthreads();
    float chi_sum = pw[0] + pw[1] + pw[2] + pw[3] + pw[4] + pw[5];
    float na      = pwc[0] + pwc[1] + pwc[2] + pwc[3] + pwc[4] + pwc[5];
    float Q = netq[m];
    float k_net = 1.f + fabsf(Q) / chi_sum;
    float chi_mean = chi_sum / na;
    float k_p = (Q > 0.f) ? k_net : 1.f;
    float k_n = (Q < 0.f) ? k_net : 1.f;
    float qj = (-k_n * c + k_p * chi_mean) * mask;
    if (ic == 0) q[idx] = qj;

    if (DO_MV) {
        if (t >= ic * 96 && t < ic * 96 + 96) qs[t - ic * 96] = qj;
        __syncthreads();
        int jv = t % 48, isub = t / 48;
        int j0 = jv * 8;
        float acc[8] = {};
        #pragma unroll 4
        for (int k = 0; k < 12; ++k) {
            int il = isub * 12 + k;
            int i = ic * 96 + il;
            h16x8 h = *(const h16x8*)&J[((size_t)m * NATOM + i) * NATOM + j0];
            float qi = qs[il];
            #pragma unroll
            for (int r = 0; r < 8; ++r) acc[r] = fmaf(qi, (float)h[r], acc[r]);
        }
        #pragma unroll
        for (int r = 0; r < 8; ++r) part[isub][j0 + r] = acc[r];
        __syncthreads();
        float s = 0.f;
        #pragma unroll
        for (int g = 0; g < 8; ++g) s += part[g][t];
        esp_part[(size_t)ic * NN + idx] = s;
    }
}

// ============ fallback: direct charge+ESP (ws too small for J) ============
template<bool DO_ESP>
__global__ __launch_bounds__(384)
void espq_kernel(const float* __restrict__ chi, const int* __restrict__ species,
                 const float* __restrict__ netq, const float* __restrict__ coords,
                 float* __restrict__ q, float* __restrict__ esp)
{
    __shared__ float red[512], redc[512];
    __shared__ float cx[NATOM], cy[NATOM], cz[NATOM], s2[NATOM], qs[NATOM];
    int m = blockIdx.x, j = threadIdx.x;
    int idx = m * NATOM + j;
    float c = chi[idx];
    int sp = species[idx];
    float mask = (sp != -1) ? 1.f : 0.f;
    red[j] = c; redc[j] = mask;
    if (j < 128) { red[NATOM + j] = 0.f; redc[NATOM + j] = 0.f; }
    __syncthreads();
    for (int s = 256; s > 0; s >>= 1) {
        if (j < s) { red[j] += red[j + s]; redc[j] += redc[j + s]; }
        __syncthreads();
    }
    float chi_sum = red[0], na = redc[0];
    float Q = netq[m];
    float k_net = 1.f + fabsf(Q) / chi_sum;
    float chi_mean = chi_sum / na;
    float k_p = (Q > 0.f) ? k_net : 1.f;
    float k_n = (Q < 0.f) ? k_net : 1.f;
    float qj = (-k_n * c + k_p * chi_mean) * mask;
    q[idx] = qj;

    if (DO_ESP) {
        float rx = coords[(size_t)idx * 3 + 0];
        float ry = coords[(size_t)idx * 3 + 1];
        float rz = coords[(size_t)idx * 3 + 2];
        cx[j] = rx; cy[j] = ry; cz[j] = rz;
        float sig = c_sigma[sp < 0 ? 7 : sp];
        s2[j] = sig * sig;
        qs[j] = qj;
        __syncthreads();
        float s2j = s2[j];
        float acc = 0.f;
        for (int i = 0; i < NATOM; ++i) {
            float dx = cx[i] - rx, dy = cy[i] - ry, dz = cz[i] - rz;
            float d2 = fmaf(dx, dx, fmaf(dy, dy, dz * dz)) + 1e-16f;
            float rs = __builtin_amdgcn_rsqf(d2);
            float d  = d2 * rs * A0_INV;
            float ss = fmaxf(s2[i] + s2j, 1e-8f);
            float x  = d * __builtin_amdgcn_rsqf(2.f * ss);
            float val = erf_fast(x) * rs * A0C;
            acc += (i == j) ? 0.f : qs[i] * val;
        }
        esp[idx] = (mask != 0.f) ? acc : 0.f;
    }
}

// ============ one-time weight conversion to bf16 (+ rank-2 columns) ============
__global__ __launch_bounds__(256)
void wcvt_kernel(const float* __restrict__ W1, const float* __restrict__ W2,
                 const float* __restrict__ W3,
                 short* __restrict__ W1b, short* __restrict__ W2b,
                 short* __restrict__ W3b, float* __restrict__ w1q,
                 float* __restrict__ w1e)
{
    int i = blockIdx.x * 256 + threadIdx.x;
    if (i < 160 * 384) {
        int r = i / 384, cc = i % 384;
        W1b[i] = f2b(W1[(size_t)r * 386 + cc]);
    }
    int j = i - 160 * 384;
    if (j >= 0 && j < 128 * 160) W2b[j] = f2b(W2[j]);
    int k2 = j - 128 * 160;
    if (k2 >= 0 && k2 < 96 * 128) W3b[k2] = f2b(W3[k2]);
    if (i < 160) {
        w1q[i] = W1[(size_t)i * 386 + 384];
        w1e[i] = W1[(size_t)i * 386 + 385];
    }
}

// ---------------- output: [species as float | charges] ----------------
__global__ __launch_bounds__(256)
void out_kernel(const int* __restrict__ species, const float* __restrict__ q,
                float* __restrict__ out)
{
    int i = blockIdx.x * 256 + threadIdx.x;
    out[i] = (float)species[i];
    out[NN + i] = q[i];
}

extern "C" void kernel_launch(void* const* d_in, const int* in_sizes, int n_in,
                              void* d_out, int out_size, void* d_ws, size_t ws_size,
                              hipStream_t stream)
{
    const int*   species = (const int*)  d_in[0];
    const float* coords  = (const float*)d_in[1];
    const float* netq    = (const float*)d_in[2];
    const float* aev     = (const float*)d_in[3];
    const float* W1 = (const float*)d_in[4];
    const float* b1 = (const float*)d_in[5];
    const float* W2 = (const float*)d_in[6];
    const float* b2 = (const float*)d_in[7];
    const float* W3 = (const float*)d_in[8];
    const float* b3 = (const float*)d_in[9];
    const float* W4 = (const float*)d_in[10];
    const float* b4 = (const float*)d_in[11];

    float* q    = (float*)d_ws;                 // NN
    float* chi  = q + NN;                       // NN
    float* espp = chi + NN;                     // 4*NN partial planes
    float* w1q  = espp + 4 * (size_t)NN;        // 160
    float* w1e  = w1q + 160;                    // 160
    short* W1b  = (short*)(w1e + 160);          // 160*384
    short* W2b  = W1b + 160 * 384;              // 128*160
    short* W3b  = W2b + 128 * 160;              // 96*128
    short* h1p  = W3b + 96 * 128;               // NN*160 bf16
    _Float16* J = (_Float16*)(h1p + (size_t)NN * 160);  // NN*384 fp16

    const size_t NEED = (size_t)((char*)(J + (size_t)NN * 384) - (char*)d_ws);
    const bool use_J = (ws_size >= NEED);

    // zero q + espp planes (iteration-0 features; unused planes stay 0 in fallback)
    hipMemsetAsync(d_ws, 0, 6 * (size_t)NN * sizeof(float), stream);
    wcvt_kernel<<<(160 * 384 + 128 * 160 + 96 * 128 + 255) / 256, 256, 0, stream>>>(
        W1, W2, W3, W1b, W2b, W3b, w1q, w1e);

    if (use_J)
        jbuild_kernel<<<dim3(NMOL, 8), 384, 0, stream>>>(coords, species, J);

    // iteration-invariant: h1p = aev @ W1[:, :384]^T + b1
    gemm0_k<160, 384><<<NN / 64, 256, 0, stream>>>(aev, W1b, b1, h1p);

    for (int it = 0; it < 4; ++it) {
        mlp23_kernel<<<NN / 64, 256, 0, stream>>>(
            h1p, W2b, b2, W3b, b3, W4, b4, q, espp, w1q, w1e, species, chi);
        if (use_J) {
            if (it < 3)
                espmv_kernel<true><<<dim3(NMOL, 4), 384, 0, stream>>>(
                    chi, species, netq, J, q, espp);
            else
                espmv_kernel<false><<<dim3(NMOL, 1), 384, 0, stream>>>(
                    chi, species, netq, J, q, espp);
        } else {
            if (it < 3)
                espq_kernel<true><<<NMOL, 384, 0, stream>>>(
                    chi, species, netq, coords, q, espp);
            else
                espq_kernel<false><<<NMOL, 384, 0, stream>>>(
                    chi, species, netq, coords, q, espp);
        }
    }

    out_kernel<<<NN / 256, 256, 0, stream>>>(species, q, (float*)d_out);
}